// Round 4
// baseline (224.937 us; speedup 1.0000x reference)
//
#include <hip/hip_runtime.h>
#include <math.h>

#define B_ 2
#define N1_ 2048
#define N2_ 512
#define CS_ 384
#define H_ 12
#define PQ_ 8
#define PV_ 12
#define PKV_ 20
#define CQ_ (H_*PQ_*3)    // 288
#define CKV_ (H_*PKV_*3)  // 720
#define INF_ 100000.0f
#define HW_SCALE_ 0.09622504486493764f   // sqrt(1/108)
#define LOG2E_ 1.4426950408889634f

typedef __attribute__((ext_vector_type(8))) short bf16x8;
typedef __attribute__((ext_vector_type(4))) float f32x4;

__device__ inline unsigned short f2bf(float x) {
  unsigned u = __float_as_uint(x);
  u += 0x7fffu + ((u >> 16) & 1u);      // RNE
  return (unsigned short)(u >> 16);
}

// convert 8 consecutive f32 -> bf16x8 fragment (two dwordx4 loads)
__device__ inline bf16x8 cvt8(const float* __restrict__ p) {
  float4 a = *(const float4*)p;
  float4 b = *(const float4*)(p + 4);
  bf16x8 r;
  r[0] = (short)f2bf(a.x); r[1] = (short)f2bf(a.y);
  r[2] = (short)f2bf(a.z); r[3] = (short)f2bf(a.w);
  r[4] = (short)f2bf(b.x); r[5] = (short)f2bf(b.y);
  r[6] = (short)f2bf(b.z); r[7] = (short)f2bf(b.w);
  return r;
}

// ---------------- prep: weight transposes + vtb pad + kn zero + s1/s2 -> bf16 ----------------
#define TQ_   108   // Wq  384x288: 12 k-tiles x 9 n-tiles
#define TKV_  276   // Wkv 384x720: 12 x 23 (guard n<720)
#define TWO_  216   // Wout 576x384: 18 x 12
#define VPAD_ 72    // vtb comps 36..47 = 0 (147456 elts, 8/thr)
#define KN_   12    // kn = 0 (12288 f32, 4/thr)
#define S1B_  768   // s1 -> bf16 (1572864 elts, 8/thr)
#define S2B_  192   // s2 -> bf16 (393216 elts, 8/thr)
#define PREP_GRID_ (TQ_+TKV_+TWO_+VPAD_+KN_+S1B_+S2B_)
__global__ __launch_bounds__(256) void prep_kernel(
    const float* __restrict__ Wq, const float* __restrict__ Wkv,
    const float* __restrict__ Wout,
    const float* __restrict__ s1, const float* __restrict__ s2,
    unsigned short* __restrict__ wqT, unsigned short* __restrict__ wkvT,
    unsigned short* __restrict__ woutT,
    unsigned short* __restrict__ vtb, float* __restrict__ kn,
    unsigned short* __restrict__ s1b, unsigned short* __restrict__ s2b)
{
  __shared__ float lds[32][33];
  int blk = blockIdx.x, t = threadIdx.x;
  int rr0 = t >> 5, cc = t & 31;

  const float* src = nullptr; unsigned short* dst = nullptr;
  int K = 0, N = 0, k0 = 0, n0 = 0;
  if (blk < TQ_) {
    src = Wq; dst = wqT; K = 384; N = CQ_;
    k0 = (blk % 12) * 32; n0 = (blk / 12) * 32;
  } else if (blk < TQ_ + TKV_) {
    int b2 = blk - TQ_;
    src = Wkv; dst = wkvT; K = 384; N = CKV_;
    k0 = (b2 % 12) * 32; n0 = (b2 / 12) * 32;
  } else if (blk < TQ_ + TKV_ + TWO_) {
    int b3 = blk - TQ_ - TKV_;
    src = Wout; dst = woutT; K = 576; N = CS_;
    k0 = (b3 % 18) * 32; n0 = (b3 / 18) * 32;
  } else if (blk < TQ_ + TKV_ + TWO_ + VPAD_) {
    int idx = (blk - TQ_ - TKV_ - TWO_)*256 + t;
    int f = idx * 8;
    int run = f >> 9, off = f & 511;
    int bh = run / 12, cc2 = 36 + run % 12;
    uint4 z = {0u,0u,0u,0u};
    *(uint4*)(vtb + ((size_t)bh*48 + cc2)*512 + off) = z;
    return;
  } else if (blk < TQ_ + TKV_ + TWO_ + VPAD_ + KN_) {
    int idx = (blk - TQ_ - TKV_ - TWO_ - VPAD_)*256 + t;
    float4 z = {0.f,0.f,0.f,0.f};
    *(float4*)(kn + (size_t)idx*4) = z;
    return;
  } else if (blk < TQ_ + TKV_ + TWO_ + VPAD_ + KN_ + S1B_) {
    size_t idx = (size_t)(blk - TQ_ - TKV_ - TWO_ - VPAD_ - KN_)*256 + t;
    *(bf16x8*)(s1b + idx*8) = cvt8(s1 + idx*8);
    return;
  } else {
    size_t idx = (size_t)(blk - TQ_ - TKV_ - TWO_ - VPAD_ - KN_ - S1B_)*256 + t;
    *(bf16x8*)(s2b + idx*8) = cvt8(s2 + idx*8);
    return;
  }

  #pragma unroll
  for (int rr = 0; rr < 4; ++rr) {
    int r = rr0 + rr*8;
    if (n0 + cc < N) lds[r][cc] = src[(size_t)(k0 + r)*N + n0 + cc];
  }
  __syncthreads();
  #pragma unroll
  for (int rr = 0; rr < 4; ++rr) {
    int r = rr0 + rr*8;
    if (n0 + r < N) dst[(size_t)(n0 + r)*K + k0 + cc] = f2bf(lds[cc][r]);
  }
}

// ---------------- fused Q + KV projection via MFMA, 2-way k-split ----------------
// 624 blocks x 512 thr (8 waves = 4 pair-slots x 2 k-halves). Blocks [0,384): Q
// (pair ids 0..1535); [384,624): KV (0..959). kh=1 wave stashes its 12 partial
// accs in LDS; kh=0 wave merges and runs the epilogue.
__global__ __launch_bounds__(512) void proj_mfma(
    const unsigned short* __restrict__ s1b, const unsigned short* __restrict__ s2b,
    const unsigned short* __restrict__ wqT, const unsigned short* __restrict__ wkvT,
    const float* __restrict__ r1_rot, const float* __restrict__ r1_trans,
    const float* __restrict__ r2_rot, const float* __restrict__ r2_trans,
    unsigned short* __restrict__ qgb, float* __restrict__ qn,
    unsigned short* __restrict__ kgb, unsigned short* __restrict__ vtb,
    float* __restrict__ kn)
{
  __shared__ float merge_s[4][64][13];   // stride 13: gcd(13,32)=1, conflict-free
  int wave = threadIdx.x >> 6, lane = threadIdx.x & 63;
  int col = lane & 15, g = lane >> 4;
  int pr = wave >> 1, kh = wave & 1;
  int k0 = kh * 192;

  if (blockIdx.x < 384) {
    // ---- Q projection ----
    int pid = blockIdx.x*4 + pr;         // 0..1535
    int strip = pid / 6;                 // 0..255
    int nt = pid % 6;
    int i0 = strip * 16;

    f32x4 ax = {0.f,0.f,0.f,0.f}, ay = ax, az = ax;
    const unsigned short* arow = s1b + (size_t)(i0 + col)*CS_ + k0;
    const unsigned short* bx = wqT + (size_t)((nt     )*16 + col)*CS_ + k0;
    const unsigned short* by = wqT + (size_t)((nt +  6)*16 + col)*CS_ + k0;
    const unsigned short* bz = wqT + (size_t)((nt + 12)*16 + col)*CS_ + k0;
    #pragma unroll
    for (int k = 0; k < 192; k += 32) {
      bf16x8 a = *(const bf16x8*)(arow + k + g*8);
      ax = __builtin_amdgcn_mfma_f32_16x16x32_bf16(a, *(const bf16x8*)(bx + k + g*8), ax, 0,0,0);
      ay = __builtin_amdgcn_mfma_f32_16x16x32_bf16(a, *(const bf16x8*)(by + k + g*8), ay, 0,0,0);
      az = __builtin_amdgcn_mfma_f32_16x16x32_bf16(a, *(const bf16x8*)(bz + k + g*8), az, 0,0,0);
    }
    if (kh) {
      #pragma unroll
      for (int r = 0; r < 4; ++r) {
        merge_s[pr][lane][r]     = ax[r];
        merge_s[pr][lane][4 + r] = ay[r];
        merge_s[pr][lane][8 + r] = az[r];
      }
    }
    __syncthreads();
    if (kh) return;
    #pragma unroll
    for (int r = 0; r < 4; ++r) {
      ax[r] += merge_s[pr][lane][r];
      ay[r] += merge_s[pr][lane][4 + r];
      az[r] += merge_s[pr][lane][8 + r];
    }

    int p = nt*16 + col;
    int h = p >> 3, pq = p & 7;
    float qsum[4];
    #pragma unroll
    for (int r = 0; r < 4; ++r) {
      int row = i0 + g*4 + r;
      const float* R  = r1_rot   + (size_t)row*9;
      const float* tr = r1_trans + (size_t)row*3;
      float x = ax[r], y = ay[r], z = az[r];
      float g0 = R[0]*x + R[1]*y + R[2]*z + tr[0];
      float g1 = R[3]*x + R[4]*y + R[5]*z + tr[1];
      float g2 = R[6]*x + R[7]*y + R[8]*z + tr[2];
      int b = row >> 11, i = row & (N1_-1);
      size_t rbase = ((size_t)(b*H_ + h)*N1_ + i)*32;
      qgb[rbase + pq*3]     = f2bf(g0);
      qgb[rbase + pq*3 + 1] = f2bf(g1);
      qgb[rbase + pq*3 + 2] = f2bf(g2);
      if (pq == 7) {
        uint4 z4 = {0u,0u,0u,0u};
        *(uint4*)(qgb + rbase + 24) = z4;
      }
      qsum[r] = g0*g0 + g1*g1 + g2*g2;
    }
    #pragma unroll
    for (int r = 0; r < 4; ++r) {
      qsum[r] += __shfl_xor(qsum[r], 1);
      qsum[r] += __shfl_xor(qsum[r], 2);
      qsum[r] += __shfl_xor(qsum[r], 4);
    }
    if ((col & 7) == 0) {
      int hh = nt*2 + (col >> 3);
      #pragma unroll
      for (int r = 0; r < 4; ++r) {
        int row = i0 + g*4 + r;
        int b = row >> 11, i = row & (N1_-1);
        qn[(size_t)(b*H_ + hh)*N1_ + i] = qsum[r];
      }
    }
  } else {
    // ---- KV projection ----
    int pid = (blockIdx.x - 384)*4 + pr;   // 0..959
    int strip = pid / 15;                  // 0..63
    int nt = pid % 15;                     // 0..14
    int row0 = strip * 16;

    f32x4 ax = {0.f,0.f,0.f,0.f}, ay = ax, az = ax;
    const unsigned short* arow = s2b + (size_t)(row0 + col)*CS_ + k0;
    const unsigned short* bx = wkvT + (size_t)(nt*16       + col)*CS_ + k0;
    const unsigned short* by = wkvT + (size_t)(nt*16 + 240 + col)*CS_ + k0;
    const unsigned short* bz = wkvT + (size_t)(nt*16 + 480 + col)*CS_ + k0;
    #pragma unroll
    for (int k = 0; k < 192; k += 32) {
      bf16x8 a = *(const bf16x8*)(arow + k + g*8);
      ax = __builtin_amdgcn_mfma_f32_16x16x32_bf16(a, *(const bf16x8*)(bx + k + g*8), ax, 0,0,0);
      ay = __builtin_amdgcn_mfma_f32_16x16x32_bf16(a, *(const bf16x8*)(by + k + g*8), ay, 0,0,0);
      az = __builtin_amdgcn_mfma_f32_16x16x32_bf16(a, *(const bf16x8*)(bz + k + g*8), az, 0,0,0);
    }
    if (kh) {
      #pragma unroll
      for (int r = 0; r < 4; ++r) {
        merge_s[pr][lane][r]     = ax[r];
        merge_s[pr][lane][4 + r] = ay[r];
        merge_s[pr][lane][8 + r] = az[r];
      }
    }
    __syncthreads();
    if (kh) return;
    #pragma unroll
    for (int r = 0; r < 4; ++r) {
      ax[r] += merge_s[pr][lane][r];
      ay[r] += merge_s[pr][lane][4 + r];
      az[r] += merge_s[pr][lane][8 + r];
    }

    int p = nt*16 + col;
    int h = p / PKV_, pp = p % PKV_;
    #pragma unroll
    for (int r = 0; r < 4; ++r) {
      int row = row0 + g*4 + r;
      const float* R  = r2_rot   + (size_t)row*9;
      const float* tr = r2_trans + (size_t)row*3;
      float x = ax[r], y = ay[r], z = az[r];
      float g0 = R[0]*x + R[1]*y + R[2]*z + tr[0];
      float g1 = R[3]*x + R[4]*y + R[5]*z + tr[1];
      float g2 = R[6]*x + R[7]*y + R[8]*z + tr[2];
      int b = row >> 9, j = row & (N2_-1);
      int bh = b*H_ + h;
      if (pp < PQ_) {
        size_t base = ((size_t)bh*N2_ + j)*32 + pp*3;
        kgb[base]   = f2bf(g0);
        kgb[base+1] = f2bf(g1);
        kgb[base+2] = f2bf(g2);
        if (pp == 0) {
          uint4 z4 = {0u,0u,0u,0u};
          *(uint4*)(kgb + ((size_t)bh*N2_ + j)*32 + 24) = z4;
        }
        atomicAdd(&kn[(size_t)bh*N2_ + j], g0*g0 + g1*g1 + g2*g2);
      } else {
        int comp = (pp - PQ_)*3;
        size_t base = ((size_t)bh*48 + comp)*512 + j;
        vtb[base]        = f2bf(g0);
        vtb[base + 512]  = f2bf(g1);
        vtb[base + 1024] = f2bf(g2);
      }
    }
  }
}

// ---------------- fused MFMA flash attention + output projection, 8-row i-tiles ----------------
// One block per (b, i-tile of 8 rows): grid 512 -> 2 blocks/CU, 24 waves/CU
// (vs 12 before: latency-bound regime, occupancy is the lever). 12 waves = 12
// heads; MFMA M=16 tiles run half-occupied (rows/cols >= 8 are clamped
// duplicates, never stored). Register prefetch pipeline retained.
#define RSTRIDE 72
#define OSTRIDE 51
#define WSLOT 3328          // max(16*72*2, 16*51*4) rounded to 16B; pstrip/o_s overlay
#define FSTRIDE 584         // 576 + 8 bf16 pad -> 16B-offset per row, conflict-free b128
__global__ __launch_bounds__(768, 6) void attn_fused(
    const unsigned short* __restrict__ qgb, const float* __restrict__ qn,
    const unsigned short* __restrict__ kgb, const unsigned short* __restrict__ vtb,
    const float* __restrict__ kn, const float* __restrict__ mask1,
    const float* __restrict__ mask2, const float* __restrict__ hwts,
    const float* __restrict__ rot, const float* __restrict__ trans,
    const unsigned short* __restrict__ woutT, const float* __restrict__ bout,
    float* __restrict__ out)
{
  __shared__ __align__(16) unsigned char ovl[12*WSLOT];          // 39936 B
  __shared__ __align__(16) unsigned short feats_s[8][FSTRIDE];   // 9344 B
  __shared__ float l_s[12][16];                                  // 768 B

  int wave = threadIdx.x >> 6;
  int lane = threadIdx.x & 63;
  int col = lane & 15, g = lane >> 4;
  int b = blockIdx.x >> 8;
  int it8 = blockIdx.x & 255;
  int i0 = it8 * 8;
  int h = wave;
  int bh = b*H_ + h;

  unsigned short* ps = (unsigned short*)(ovl + wave*WSLOT);  // [16][RSTRIDE] u16
  float*          os = (float*)(ovl + wave*WSLOT);           // [16][OSTRIDE] f32 (after last ps use)

  float hw   = logf(1.0f + __expf(hwts[h])) * HW_SCALE_;
  float hwl  = hw * LOG2E_;                 // log2-domain scale
  float mneg = -INF_ * LOG2E_;

  // Q rows: 8 valid rows, lanes col>=8 duplicate rows 0..7 (outputs discarded)
  bf16x8 qa = *(const bf16x8*)(qgb + (((size_t)bh*N1_ + i0 + (col & 7))*32 + g*8));

  float ar[4], m1l[4];
  #pragma unroll
  for (int r = 0; r < 4; ++r) {
    int ig = i0 + ((g*4 + r) & 7);        // rows 8..15 clamp to dup of 0..7
    ar[r]  = -0.5f*hwl * qn[(size_t)bh*N1_ + ig];
    m1l[r] = mask1[b*N1_ + ig] * (INF_*LOG2E_);   // fma(m1l, m2, mneg) == 0 exactly when unmasked
  }

  f32x4 ot[3];
  #pragma unroll
  for (int m = 0; m < 3; ++m) ot[m] = (f32x4){0.f,0.f,0.f,0.f};
  float l[4] = {0.f,0.f,0.f,0.f};

  const unsigned short* kbase = kgb + (size_t)bh*N2_*32;
  const unsigned short* vbase = vtb + (size_t)bh*48*512;
  const float* knp = kn + (size_t)bh*N2_;
  const float* m2p = mask2 + b*N2_;

  // ---- software pipeline: register-prefetch next j-tile's K/V/scalars ----
  bf16x8 kbuf[4], vbuf[6];
  float knb[4], m2b[4];
  #pragma unroll
  for (int nt = 0; nt < 4; ++nt) {
    int jg = nt*16 + col;
    kbuf[nt] = *(const bf16x8*)(kbase + ((size_t)jg*32 + g*8));
    knb[nt] = knp[jg];
    m2b[nt] = m2p[jg];
  }
  #pragma unroll
  for (int ks = 0; ks < 2; ++ks)
    #pragma unroll
    for (int mtv = 0; mtv < 3; ++mtv)
      vbuf[ks*3 + mtv] = *(const bf16x8*)(vbase +
          ((size_t)(mtv*16 + col))*512 + ks*32 + g*8);

  for (int jt = 0; jt < 8; ++jt) {
    int j0 = jt*64;
    bf16x8 kNx[4], vNx[6];
    float knN[4], m2N[4];
    if (jt < 7) {
      int j1 = j0 + 64;
      #pragma unroll
      for (int nt = 0; nt < 4; ++nt) {
        int jg = j1 + nt*16 + col;
        kNx[nt] = *(const bf16x8*)(kbase + ((size_t)jg*32 + g*8));
        knN[nt] = knp[jg];
        m2N[nt] = m2p[jg];
      }
      #pragma unroll
      for (int ks = 0; ks < 2; ++ks)
        #pragma unroll
        for (int mtv = 0; mtv < 3; ++mtv)
          vNx[ks*3 + mtv] = *(const bf16x8*)(vbase +
              ((size_t)(mtv*16 + col))*512 + j1 + ks*32 + g*8);
    }

    #pragma unroll
    for (int nt = 0; nt < 4; ++nt) {
      f32x4 dotv = __builtin_amdgcn_mfma_f32_16x16x32_bf16(
          qa, kbuf[nt], (f32x4){0.f,0.f,0.f,0.f}, 0, 0, 0);
      float bc  = -0.5f*hwl*knb[nt];
      float m2c = m2b[nt];
      #pragma unroll
      for (int r = 0; r < 4; ++r) {
        float logit = fmaf(hwl, dotv[r], fmaf(m1l[r], m2c, mneg) + (ar[r] + bc));
        float w = __builtin_amdgcn_exp2f(logit);   // logit <= 0 -> w <= 1
        l[r] += w;
        ps[(g*4 + r)*RSTRIDE + nt*16 + col] = f2bf(w);
      }
    }
    #pragma unroll
    for (int ks = 0; ks < 2; ++ks) {
      bf16x8 pb = *(const bf16x8*)&ps[col*RSTRIDE + ks*32 + g*8];
      #pragma unroll
      for (int mtv = 0; mtv < 3; ++mtv)
        ot[mtv] = __builtin_amdgcn_mfma_f32_16x16x32_bf16(vbuf[ks*3 + mtv], pb, ot[mtv], 0, 0, 0);
    }

    if (jt < 7) {
      #pragma unroll
      for (int i = 0; i < 4; ++i) { kbuf[i] = kNx[i]; knb[i] = knN[i]; m2b[i] = m2N[i]; }
      #pragma unroll
      for (int i = 0; i < 6; ++i) vbuf[i] = vNx[i];
    }
  }

  // reduce l over the 16 cols; stash l and O partials in LDS
  #pragma unroll
  for (int r = 0; r < 4; ++r) {
    l[r] += __shfl_xor(l[r], 1);
    l[r] += __shfl_xor(l[r], 2);
    l[r] += __shfl_xor(l[r], 4);
    l[r] += __shfl_xor(l[r], 8);
  }
  __builtin_amdgcn_sched_barrier(0);   // keep os writes after the final ps reads
  if (col == 0) {
    #pragma unroll
    for (int r = 0; r < 4; ++r) l_s[wave][g*4 + r] = l[r];
  }
  #pragma unroll
  for (int mtv = 0; mtv < 3; ++mtv)
    #pragma unroll
    for (int r = 0; r < 4; ++r)
      os[col*OSTRIDE + mtv*16 + g*4 + r] = ot[mtv][r];
  __syncthreads();

  // epilogue: rotate back to local frame, write bf16 feats slice to LDS (8 rows)
  if (col < 8) {
    float inv = 1.0f / l_s[wave][col];
    int row = b*N1_ + i0 + col;
    const float* R  = rot   + (size_t)row*9;
    const float* tr = trans + (size_t)row*3;
    float R00=R[0],R01=R[1],R02=R[2],R10=R[3],R11=R[4],R12=R[5],R20=R[6],R21=R[7],R22=R[8];
    float t0=tr[0], t1=tr[1], t2=tr[2];
    int h12 = h*PV_;
    #pragma unroll
    for (int p = 0; p < 3; ++p) {
      int pt = g*3 + p;
      float ox = os[col*OSTRIDE + pt*3+0]*inv - t0;
      float oy = os[col*OSTRIDE + pt*3+1]*inv - t1;
      float oz = os[col*OSTRIDE + pt*3+2]*inv - t2;
      float lx = R00*ox + R10*oy + R20*oz;
      float ly = R01*ox + R11*oy + R21*oz;
      float lz = R02*ox + R12*oy + R22*oz;
      float dist = sqrtf(lx*lx + ly*ly + lz*lz + 1e-8f);
      feats_s[col][      h12 + pt] = f2bf(lx);
      feats_s[col][144 + h12 + pt] = f2bf(ly);
      feats_s[col][288 + h12 + pt] = f2bf(lz);
      feats_s[col][432 + h12 + pt] = f2bf(dist);
    }
  }
  __syncthreads();

  // output projection: wave handles cols [wave*32, wave*32+32) of out (8 rows)
  {
    int n0 = wave * 32;
    f32x4 acc0 = {0.f,0.f,0.f,0.f}, acc1 = acc0;
    const unsigned short* b0 = woutT + (size_t)(n0      + col)*576;
    const unsigned short* b1 = woutT + (size_t)(n0 + 16 + col)*576;
    #pragma unroll 3
    for (int k = 0; k < 576; k += 32) {
      bf16x8 a = *(const bf16x8*)&feats_s[col & 7][k + g*8];
      acc0 = __builtin_amdgcn_mfma_f32_16x16x32_bf16(a, *(const bf16x8*)(b0 + k + g*8), acc0, 0,0,0);
      acc1 = __builtin_amdgcn_mfma_f32_16x16x32_bf16(a, *(const bf16x8*)(b1 + k + g*8), acc1, 0,0,0);
    }
    if (g < 2) {                         // rows g*4+r in [0,8)
      int rowbase = b*N1_ + i0;
      float bb0 = bout[n0 + col];
      float bb1 = bout[n0 + 16 + col];
      #pragma unroll
      for (int r = 0; r < 4; ++r) {
        size_t orow = (size_t)(rowbase + g*4 + r)*CS_;
        out[orow + n0 + col]      = acc0[r] + bb0;
        out[orow + n0 + 16 + col] = acc1[r] + bb1;
      }
    }
  }
}

extern "C" void kernel_launch(void* const* d_in, const int* in_sizes, int n_in,
                              void* d_out, int out_size, void* d_ws, size_t ws_size,
                              hipStream_t stream) {
  const float* s1       = (const float*)d_in[0];
  const float* s2       = (const float*)d_in[1];
  const float* r1_rot   = (const float*)d_in[2];
  const float* r1_trans = (const float*)d_in[3];
  const float* r2_rot   = (const float*)d_in[4];
  const float* r2_trans = (const float*)d_in[5];
  const float* mask1    = (const float*)d_in[6];
  const float* mask2    = (const float*)d_in[7];
  const float* Wq       = (const float*)d_in[8];
  const float* Wkv      = (const float*)d_in[9];
  const float* hwts     = (const float*)d_in[10];
  const float* Wout     = (const float*)d_in[11];
  const float* bout     = (const float*)d_in[12];
  float* out = (float*)d_out;

  float* qn = (float*)d_ws;                              // 49152 f32
  float* kn = qn + (size_t)B_*H_*N1_;                    // 12288 f32
  unsigned short* qgb  = (unsigned short*)(kn + (size_t)B_*H_*N2_); // 1572864 u16
  unsigned short* kgb  = qgb  + (size_t)B_*H_*N1_*32;    // 393216 u16
  unsigned short* vtb  = kgb  + (size_t)B_*H_*N2_*32;    // 589824 u16
  unsigned short* wqT  = vtb  + (size_t)B_*H_*48*512;    // 110592 u16
  unsigned short* wkvT = wqT  + (size_t)CQ_*CS_;         // 276480 u16
  unsigned short* woutT= wkvT + (size_t)CKV_*CS_;        // 221184 u16
  unsigned short* s1b  = woutT+ (size_t)CS_*576;         // 1572864 u16
  unsigned short* s2b  = s1b  + (size_t)B_*N1_*CS_;      // 393216 u16

  prep_kernel<<<PREP_GRID_, 256, 0, stream>>>(
      Wq, Wkv, Wout, s1, s2, wqT, wkvT, woutT, vtb, kn, s1b, s2b);
  proj_mfma<<<624, 512, 0, stream>>>(s1b, s2b, wqT, wkvT, r1_rot, r1_trans,
                                     r2_rot, r2_trans, qgb, qn, kgb, vtb, kn);
  attn_fused<<<B_*(N1_/8), 768, 0, stream>>>(qgb, qn, kgb, vtb, kn, mask1, mask2,
                                             hwts, r1_rot, r1_trans, woutT, bout, out);
}

// Round 5
// 179.807 us; speedup vs baseline: 1.2510x; 1.2510x over previous
//
#include <hip/hip_runtime.h>
#include <math.h>

#define B_ 2
#define N1_ 2048
#define N2_ 512
#define CS_ 384
#define H_ 12
#define PQ_ 8
#define PV_ 12
#define PKV_ 20
#define CQ_ (H_*PQ_*3)    // 288
#define CKV_ (H_*PKV_*3)  // 720
#define INF_ 100000.0f
#define HW_SCALE_ 0.09622504486493764f   // sqrt(1/108)
#define LOG2E_ 1.4426950408889634f

typedef __attribute__((ext_vector_type(8))) short bf16x8;
typedef __attribute__((ext_vector_type(4))) float f32x4;

__device__ inline unsigned short f2bf(float x) {
  unsigned u = __float_as_uint(x);
  u += 0x7fffu + ((u >> 16) & 1u);      // RNE
  return (unsigned short)(u >> 16);
}

// convert 8 consecutive f32 -> bf16x8 fragment (two dwordx4 loads)
__device__ inline bf16x8 cvt8(const float* __restrict__ p) {
  float4 a = *(const float4*)p;
  float4 b = *(const float4*)(p + 4);
  bf16x8 r;
  r[0] = (short)f2bf(a.x); r[1] = (short)f2bf(a.y);
  r[2] = (short)f2bf(a.z); r[3] = (short)f2bf(a.w);
  r[4] = (short)f2bf(b.x); r[5] = (short)f2bf(b.y);
  r[6] = (short)f2bf(b.z); r[7] = (short)f2bf(b.w);
  return r;
}

// ---------------- prep: weight transposes + vtb pad + kn zero + s1/s2 -> bf16 ----------------
#define TQ_   108   // Wq  384x288: 12 k-tiles x 9 n-tiles
#define TKV_  276   // Wkv 384x720: 12 x 23 (guard n<720)
#define TWO_  216   // Wout 576x384: 18 x 12
#define VPAD_ 72    // vtb comps 36..47 = 0 (147456 elts, 8/thr)
#define KN_   12    // kn = 0 (12288 f32, 4/thr)
#define S1B_  768   // s1 -> bf16 (1572864 elts, 8/thr)
#define S2B_  192   // s2 -> bf16 (393216 elts, 8/thr)
#define PREP_GRID_ (TQ_+TKV_+TWO_+VPAD_+KN_+S1B_+S2B_)
__global__ __launch_bounds__(256) void prep_kernel(
    const float* __restrict__ Wq, const float* __restrict__ Wkv,
    const float* __restrict__ Wout,
    const float* __restrict__ s1, const float* __restrict__ s2,
    unsigned short* __restrict__ wqT, unsigned short* __restrict__ wkvT,
    unsigned short* __restrict__ woutT,
    unsigned short* __restrict__ vtb, float* __restrict__ kn,
    unsigned short* __restrict__ s1b, unsigned short* __restrict__ s2b)
{
  __shared__ float lds[32][33];
  int blk = blockIdx.x, t = threadIdx.x;
  int rr0 = t >> 5, cc = t & 31;

  const float* src = nullptr; unsigned short* dst = nullptr;
  int K = 0, N = 0, k0 = 0, n0 = 0;
  if (blk < TQ_) {
    src = Wq; dst = wqT; K = 384; N = CQ_;
    k0 = (blk % 12) * 32; n0 = (blk / 12) * 32;
  } else if (blk < TQ_ + TKV_) {
    int b2 = blk - TQ_;
    src = Wkv; dst = wkvT; K = 384; N = CKV_;
    k0 = (b2 % 12) * 32; n0 = (b2 / 12) * 32;
  } else if (blk < TQ_ + TKV_ + TWO_) {
    int b3 = blk - TQ_ - TKV_;
    src = Wout; dst = woutT; K = 576; N = CS_;
    k0 = (b3 % 18) * 32; n0 = (b3 / 18) * 32;
  } else if (blk < TQ_ + TKV_ + TWO_ + VPAD_) {
    int idx = (blk - TQ_ - TKV_ - TWO_)*256 + t;
    int f = idx * 8;
    int run = f >> 9, off = f & 511;
    int bh = run / 12, cc2 = 36 + run % 12;
    uint4 z = {0u,0u,0u,0u};
    *(uint4*)(vtb + ((size_t)bh*48 + cc2)*512 + off) = z;
    return;
  } else if (blk < TQ_ + TKV_ + TWO_ + VPAD_ + KN_) {
    int idx = (blk - TQ_ - TKV_ - TWO_ - VPAD_)*256 + t;
    float4 z = {0.f,0.f,0.f,0.f};
    *(float4*)(kn + (size_t)idx*4) = z;
    return;
  } else if (blk < TQ_ + TKV_ + TWO_ + VPAD_ + KN_ + S1B_) {
    size_t idx = (size_t)(blk - TQ_ - TKV_ - TWO_ - VPAD_ - KN_)*256 + t;
    *(bf16x8*)(s1b + idx*8) = cvt8(s1 + idx*8);
    return;
  } else {
    size_t idx = (size_t)(blk - TQ_ - TKV_ - TWO_ - VPAD_ - KN_ - S1B_)*256 + t;
    *(bf16x8*)(s2b + idx*8) = cvt8(s2 + idx*8);
    return;
  }

  #pragma unroll
  for (int rr = 0; rr < 4; ++rr) {
    int r = rr0 + rr*8;
    if (n0 + cc < N) lds[r][cc] = src[(size_t)(k0 + r)*N + n0 + cc];
  }
  __syncthreads();
  #pragma unroll
  for (int rr = 0; rr < 4; ++rr) {
    int r = rr0 + rr*8;
    if (n0 + r < N) dst[(size_t)(n0 + r)*K + k0 + cc] = f2bf(lds[cc][r]);
  }
}

// ---------------- fused Q + KV projection via MFMA, 2-way k-split ----------------
// 624 blocks x 512 thr (8 waves = 4 pair-slots x 2 k-halves). Blocks [0,384): Q
// (pair ids 0..1535); [384,624): KV (0..959). kh=1 wave stashes its 12 partial
// accs in LDS; kh=0 wave merges and runs the epilogue.
__global__ __launch_bounds__(512) void proj_mfma(
    const unsigned short* __restrict__ s1b, const unsigned short* __restrict__ s2b,
    const unsigned short* __restrict__ wqT, const unsigned short* __restrict__ wkvT,
    const float* __restrict__ r1_rot, const float* __restrict__ r1_trans,
    const float* __restrict__ r2_rot, const float* __restrict__ r2_trans,
    unsigned short* __restrict__ qgb, float* __restrict__ qn,
    unsigned short* __restrict__ kgb, unsigned short* __restrict__ vtb,
    float* __restrict__ kn)
{
  __shared__ float merge_s[4][64][13];   // stride 13: gcd(13,32)=1, conflict-free
  int wave = threadIdx.x >> 6, lane = threadIdx.x & 63;
  int col = lane & 15, g = lane >> 4;
  int pr = wave >> 1, kh = wave & 1;
  int k0 = kh * 192;

  if (blockIdx.x < 384) {
    // ---- Q projection ----
    int pid = blockIdx.x*4 + pr;         // 0..1535
    int strip = pid / 6;                 // 0..255
    int nt = pid % 6;
    int i0 = strip * 16;

    f32x4 ax = {0.f,0.f,0.f,0.f}, ay = ax, az = ax;
    const unsigned short* arow = s1b + (size_t)(i0 + col)*CS_ + k0;
    const unsigned short* bx = wqT + (size_t)((nt     )*16 + col)*CS_ + k0;
    const unsigned short* by = wqT + (size_t)((nt +  6)*16 + col)*CS_ + k0;
    const unsigned short* bz = wqT + (size_t)((nt + 12)*16 + col)*CS_ + k0;
    #pragma unroll
    for (int k = 0; k < 192; k += 32) {
      bf16x8 a = *(const bf16x8*)(arow + k + g*8);
      ax = __builtin_amdgcn_mfma_f32_16x16x32_bf16(a, *(const bf16x8*)(bx + k + g*8), ax, 0,0,0);
      ay = __builtin_amdgcn_mfma_f32_16x16x32_bf16(a, *(const bf16x8*)(by + k + g*8), ay, 0,0,0);
      az = __builtin_amdgcn_mfma_f32_16x16x32_bf16(a, *(const bf16x8*)(bz + k + g*8), az, 0,0,0);
    }
    if (kh) {
      #pragma unroll
      for (int r = 0; r < 4; ++r) {
        merge_s[pr][lane][r]     = ax[r];
        merge_s[pr][lane][4 + r] = ay[r];
        merge_s[pr][lane][8 + r] = az[r];
      }
    }
    __syncthreads();
    if (kh) return;
    #pragma unroll
    for (int r = 0; r < 4; ++r) {
      ax[r] += merge_s[pr][lane][r];
      ay[r] += merge_s[pr][lane][4 + r];
      az[r] += merge_s[pr][lane][8 + r];
    }

    int p = nt*16 + col;
    int h = p >> 3, pq = p & 7;
    float qsum[4];
    #pragma unroll
    for (int r = 0; r < 4; ++r) {
      int row = i0 + g*4 + r;
      const float* R  = r1_rot   + (size_t)row*9;
      const float* tr = r1_trans + (size_t)row*3;
      float x = ax[r], y = ay[r], z = az[r];
      float g0 = R[0]*x + R[1]*y + R[2]*z + tr[0];
      float g1 = R[3]*x + R[4]*y + R[5]*z + tr[1];
      float g2 = R[6]*x + R[7]*y + R[8]*z + tr[2];
      int b = row >> 11, i = row & (N1_-1);
      size_t rbase = ((size_t)(b*H_ + h)*N1_ + i)*32;
      qgb[rbase + pq*3]     = f2bf(g0);
      qgb[rbase + pq*3 + 1] = f2bf(g1);
      qgb[rbase + pq*3 + 2] = f2bf(g2);
      if (pq == 7) {
        uint4 z4 = {0u,0u,0u,0u};
        *(uint4*)(qgb + rbase + 24) = z4;
      }
      qsum[r] = g0*g0 + g1*g1 + g2*g2;
    }
    #pragma unroll
    for (int r = 0; r < 4; ++r) {
      qsum[r] += __shfl_xor(qsum[r], 1);
      qsum[r] += __shfl_xor(qsum[r], 2);
      qsum[r] += __shfl_xor(qsum[r], 4);
    }
    if ((col & 7) == 0) {
      int hh = nt*2 + (col >> 3);
      #pragma unroll
      for (int r = 0; r < 4; ++r) {
        int row = i0 + g*4 + r;
        int b = row >> 11, i = row & (N1_-1);
        qn[(size_t)(b*H_ + hh)*N1_ + i] = qsum[r];
      }
    }
  } else {
    // ---- KV projection ----
    int pid = (blockIdx.x - 384)*4 + pr;   // 0..959
    int strip = pid / 15;                  // 0..63
    int nt = pid % 15;                     // 0..14
    int row0 = strip * 16;

    f32x4 ax = {0.f,0.f,0.f,0.f}, ay = ax, az = ax;
    const unsigned short* arow = s2b + (size_t)(row0 + col)*CS_ + k0;
    const unsigned short* bx = wkvT + (size_t)(nt*16       + col)*CS_ + k0;
    const unsigned short* by = wkvT + (size_t)(nt*16 + 240 + col)*CS_ + k0;
    const unsigned short* bz = wkvT + (size_t)(nt*16 + 480 + col)*CS_ + k0;
    #pragma unroll
    for (int k = 0; k < 192; k += 32) {
      bf16x8 a = *(const bf16x8*)(arow + k + g*8);
      ax = __builtin_amdgcn_mfma_f32_16x16x32_bf16(a, *(const bf16x8*)(bx + k + g*8), ax, 0,0,0);
      ay = __builtin_amdgcn_mfma_f32_16x16x32_bf16(a, *(const bf16x8*)(by + k + g*8), ay, 0,0,0);
      az = __builtin_amdgcn_mfma_f32_16x16x32_bf16(a, *(const bf16x8*)(bz + k + g*8), az, 0,0,0);
    }
    if (kh) {
      #pragma unroll
      for (int r = 0; r < 4; ++r) {
        merge_s[pr][lane][r]     = ax[r];
        merge_s[pr][lane][4 + r] = ay[r];
        merge_s[pr][lane][8 + r] = az[r];
      }
    }
    __syncthreads();
    if (kh) return;
    #pragma unroll
    for (int r = 0; r < 4; ++r) {
      ax[r] += merge_s[pr][lane][r];
      ay[r] += merge_s[pr][lane][4 + r];
      az[r] += merge_s[pr][lane][8 + r];
    }

    int p = nt*16 + col;
    int h = p / PKV_, pp = p % PKV_;
    #pragma unroll
    for (int r = 0; r < 4; ++r) {
      int row = row0 + g*4 + r;
      const float* R  = r2_rot   + (size_t)row*9;
      const float* tr = r2_trans + (size_t)row*3;
      float x = ax[r], y = ay[r], z = az[r];
      float g0 = R[0]*x + R[1]*y + R[2]*z + tr[0];
      float g1 = R[3]*x + R[4]*y + R[5]*z + tr[1];
      float g2 = R[6]*x + R[7]*y + R[8]*z + tr[2];
      int b = row >> 9, j = row & (N2_-1);
      int bh = b*H_ + h;
      if (pp < PQ_) {
        size_t base = ((size_t)bh*N2_ + j)*32 + pp*3;
        kgb[base]   = f2bf(g0);
        kgb[base+1] = f2bf(g1);
        kgb[base+2] = f2bf(g2);
        if (pp == 0) {
          uint4 z4 = {0u,0u,0u,0u};
          *(uint4*)(kgb + ((size_t)bh*N2_ + j)*32 + 24) = z4;
        }
        atomicAdd(&kn[(size_t)bh*N2_ + j], g0*g0 + g1*g1 + g2*g2);
      } else {
        int comp = (pp - PQ_)*3;
        size_t base = ((size_t)bh*48 + comp)*512 + j;
        vtb[base]        = f2bf(g0);
        vtb[base + 512]  = f2bf(g1);
        vtb[base + 1024] = f2bf(g2);
      }
    }
  }
}

// ---------------- fused MFMA flash attention + output projection, 8-row i-tiles ----------------
// One block per (b, i-tile of 8 rows): grid 512 -> 2 blocks/CU, 24 waves/CU.
// 12 waves = 12 heads; MFMA M=16 tiles run half-occupied (rows >= 8 are clamped
// duplicates, never stored). NO register prefetch: under the 6-wave/SIMD VGPR
// cap (~85) the 40-reg prefetch double-buffer spilled to scratch in round 4
// (WRITE_SIZE 6 MB -> 116 MB). Inline loads compile to ~52 VGPR -> no spill.
#define RSTRIDE 72
#define OSTRIDE 51
#define WSLOT 3328          // max(16*72*2, 16*51*4) rounded to 16B; pstrip/o_s overlay
#define FSTRIDE 584         // 576 + 8 bf16 pad -> 16B-offset per row, conflict-free b128
__global__ __launch_bounds__(768, 6) void attn_fused(
    const unsigned short* __restrict__ qgb, const float* __restrict__ qn,
    const unsigned short* __restrict__ kgb, const unsigned short* __restrict__ vtb,
    const float* __restrict__ kn, const float* __restrict__ mask1,
    const float* __restrict__ mask2, const float* __restrict__ hwts,
    const float* __restrict__ rot, const float* __restrict__ trans,
    const unsigned short* __restrict__ woutT, const float* __restrict__ bout,
    float* __restrict__ out)
{
  __shared__ __align__(16) unsigned char ovl[12*WSLOT];          // 39936 B
  __shared__ __align__(16) unsigned short feats_s[8][FSTRIDE];   // 9344 B
  __shared__ float l_s[12][16];                                  // 768 B

  int wave = threadIdx.x >> 6;
  int lane = threadIdx.x & 63;
  int col = lane & 15, g = lane >> 4;
  int b = blockIdx.x >> 8;
  int it8 = blockIdx.x & 255;
  int i0 = it8 * 8;
  int h = wave;
  int bh = b*H_ + h;

  unsigned short* ps = (unsigned short*)(ovl + wave*WSLOT);  // [16][RSTRIDE] u16
  float*          os = (float*)(ovl + wave*WSLOT);           // [16][OSTRIDE] f32 (after last ps use)

  float hw   = logf(1.0f + __expf(hwts[h])) * HW_SCALE_;
  float hwl  = hw * LOG2E_;                 // log2-domain scale
  float mneg = -INF_ * LOG2E_;

  // Q rows: 8 valid rows, lanes col>=8 duplicate rows 0..7 (outputs discarded)
  bf16x8 qa = *(const bf16x8*)(qgb + (((size_t)bh*N1_ + i0 + (col & 7))*32 + g*8));

  float ar[4], m1l[4];
  #pragma unroll
  for (int r = 0; r < 4; ++r) {
    int ig = i0 + ((g*4 + r) & 7);        // rows 8..15 clamp to dup of 0..7
    ar[r]  = -0.5f*hwl * qn[(size_t)bh*N1_ + ig];
    m1l[r] = mask1[b*N1_ + ig] * (INF_*LOG2E_);   // fma(m1l, m2, mneg) == 0 exactly when unmasked
  }

  f32x4 ot[3];
  #pragma unroll
  for (int m = 0; m < 3; ++m) ot[m] = (f32x4){0.f,0.f,0.f,0.f};
  float l[4] = {0.f,0.f,0.f,0.f};

  const unsigned short* kbase = kgb + (size_t)bh*N2_*32;
  const unsigned short* vbase = vtb + (size_t)bh*48*512;
  const float* knp = kn + (size_t)bh*N2_;
  const float* m2p = mask2 + b*N2_;

  for (int jt = 0; jt < 8; ++jt) {
    int j0 = jt*64;
    #pragma unroll
    for (int nt = 0; nt < 4; ++nt) {
      int jg = j0 + nt*16 + col;
      bf16x8 kb = *(const bf16x8*)(kbase + ((size_t)jg*32 + g*8));
      f32x4 dotv = __builtin_amdgcn_mfma_f32_16x16x32_bf16(
          qa, kb, (f32x4){0.f,0.f,0.f,0.f}, 0, 0, 0);
      float bc  = -0.5f*hwl*knp[jg];
      float m2c = m2p[jg];
      #pragma unroll
      for (int r = 0; r < 4; ++r) {
        float logit = fmaf(hwl, dotv[r], fmaf(m1l[r], m2c, mneg) + (ar[r] + bc));
        float w = __builtin_amdgcn_exp2f(logit);   // logit <= 0 -> w <= 1
        l[r] += w;
        ps[(g*4 + r)*RSTRIDE + nt*16 + col] = f2bf(w);
      }
    }
    #pragma unroll
    for (int ks = 0; ks < 2; ++ks) {
      bf16x8 pb = *(const bf16x8*)&ps[col*RSTRIDE + ks*32 + g*8];
      #pragma unroll
      for (int mtv = 0; mtv < 3; ++mtv) {
        bf16x8 va = *(const bf16x8*)(vbase +
            ((size_t)(mtv*16 + col))*512 + j0 + ks*32 + g*8);
        ot[mtv] = __builtin_amdgcn_mfma_f32_16x16x32_bf16(va, pb, ot[mtv], 0, 0, 0);
      }
    }
  }

  // reduce l over the 16 cols; stash l and O partials in LDS
  #pragma unroll
  for (int r = 0; r < 4; ++r) {
    l[r] += __shfl_xor(l[r], 1);
    l[r] += __shfl_xor(l[r], 2);
    l[r] += __shfl_xor(l[r], 4);
    l[r] += __shfl_xor(l[r], 8);
  }
  __builtin_amdgcn_sched_barrier(0);   // keep os writes after the final ps reads
  if (col == 0) {
    #pragma unroll
    for (int r = 0; r < 4; ++r) l_s[wave][g*4 + r] = l[r];
  }
  #pragma unroll
  for (int mtv = 0; mtv < 3; ++mtv)
    #pragma unroll
    for (int r = 0; r < 4; ++r)
      os[col*OSTRIDE + mtv*16 + g*4 + r] = ot[mtv][r];
  __syncthreads();

  // epilogue: rotate back to local frame, write bf16 feats slice to LDS (8 rows)
  if (col < 8) {
    float inv = 1.0f / l_s[wave][col];
    int row = b*N1_ + i0 + col;
    const float* R  = rot   + (size_t)row*9;
    const float* tr = trans + (size_t)row*3;
    float R00=R[0],R01=R[1],R02=R[2],R10=R[3],R11=R[4],R12=R[5],R20=R[6],R21=R[7],R22=R[8];
    float t0=tr[0], t1=tr[1], t2=tr[2];
    int h12 = h*PV_;
    #pragma unroll
    for (int p = 0; p < 3; ++p) {
      int pt = g*3 + p;
      float ox = os[col*OSTRIDE + pt*3+0]*inv - t0;
      float oy = os[col*OSTRIDE + pt*3+1]*inv - t1;
      float oz = os[col*OSTRIDE + pt*3+2]*inv - t2;
      float lx = R00*ox + R10*oy + R20*oz;
      float ly = R01*ox + R11*oy + R21*oz;
      float lz = R02*ox + R12*oy + R22*oz;
      float dist = sqrtf(lx*lx + ly*ly + lz*lz + 1e-8f);
      feats_s[col][      h12 + pt] = f2bf(lx);
      feats_s[col][144 + h12 + pt] = f2bf(ly);
      feats_s[col][288 + h12 + pt] = f2bf(lz);
      feats_s[col][432 + h12 + pt] = f2bf(dist);
    }
  }
  __syncthreads();

  // output projection: wave handles cols [wave*32, wave*32+32) of out (8 rows)
  {
    int n0 = wave * 32;
    f32x4 acc0 = {0.f,0.f,0.f,0.f}, acc1 = acc0;
    const unsigned short* b0 = woutT + (size_t)(n0      + col)*576;
    const unsigned short* b1 = woutT + (size_t)(n0 + 16 + col)*576;
    #pragma unroll 3
    for (int k = 0; k < 576; k += 32) {
      bf16x8 a = *(const bf16x8*)&feats_s[col & 7][k + g*8];
      acc0 = __builtin_amdgcn_mfma_f32_16x16x32_bf16(a, *(const bf16x8*)(b0 + k + g*8), acc0, 0,0,0);
      acc1 = __builtin_amdgcn_mfma_f32_16x16x32_bf16(a, *(const bf16x8*)(b1 + k + g*8), acc1, 0,0,0);
    }
    if (g < 2) {                         // rows g*4+r in [0,8)
      int rowbase = b*N1_ + i0;
      float bb0 = bout[n0 + col];
      float bb1 = bout[n0 + 16 + col];
      #pragma unroll
      for (int r = 0; r < 4; ++r) {
        size_t orow = (size_t)(rowbase + g*4 + r)*CS_;
        out[orow + n0 + col]      = acc0[r] + bb0;
        out[orow + n0 + 16 + col] = acc1[r] + bb1;
      }
    }
  }
}

extern "C" void kernel_launch(void* const* d_in, const int* in_sizes, int n_in,
                              void* d_out, int out_size, void* d_ws, size_t ws_size,
                              hipStream_t stream) {
  const float* s1       = (const float*)d_in[0];
  const float* s2       = (const float*)d_in[1];
  const float* r1_rot   = (const float*)d_in[2];
  const float* r1_trans = (const float*)d_in[3];
  const float* r2_rot   = (const float*)d_in[4];
  const float* r2_trans = (const float*)d_in[5];
  const float* mask1    = (const float*)d_in[6];
  const float* mask2    = (const float*)d_in[7];
  const float* Wq       = (const float*)d_in[8];
  const float* Wkv      = (const float*)d_in[9];
  const float* hwts     = (const float*)d_in[10];
  const float* Wout     = (const float*)d_in[11];
  const float* bout     = (const float*)d_in[12];
  float* out = (float*)d_out;

  float* qn = (float*)d_ws;                              // 49152 f32
  float* kn = qn + (size_t)B_*H_*N1_;                    // 12288 f32
  unsigned short* qgb  = (unsigned short*)(kn + (size_t)B_*H_*N2_); // 1572864 u16
  unsigned short* kgb  = qgb  + (size_t)B_*H_*N1_*32;    // 393216 u16
  unsigned short* vtb  = kgb  + (size_t)B_*H_*N2_*32;    // 589824 u16
  unsigned short* wqT  = vtb  + (size_t)B_*H_*48*512;    // 110592 u16
  unsigned short* wkvT = wqT  + (size_t)CQ_*CS_;         // 276480 u16
  unsigned short* woutT= wkvT + (size_t)CKV_*CS_;        // 221184 u16
  unsigned short* s1b  = woutT+ (size_t)CS_*576;         // 1572864 u16
  unsigned short* s2b  = s1b  + (size_t)B_*N1_*CS_;      // 393216 u16

  prep_kernel<<<PREP_GRID_, 256, 0, stream>>>(
      Wq, Wkv, Wout, s1, s2, wqT, wkvT, woutT, vtb, kn, s1b, s2b);
  proj_mfma<<<624, 512, 0, stream>>>(s1b, s2b, wqT, wkvT, r1_rot, r1_trans,
                                     r2_rot, r2_trans, qgb, qn, kgb, vtb, kn);
  attn_fused<<<B_*(N1_/8), 768, 0, stream>>>(qgb, qn, kgb, vtb, kn, mask1, mask2,
                                             hwts, r1_rot, r1_trans, woutT, bout, out);
}

// Round 6
// 152.060 us; speedup vs baseline: 1.4793x; 1.1825x over previous
//
#include <hip/hip_runtime.h>
#include <math.h>

#define B_ 2
#define N1_ 2048
#define N2_ 512
#define CS_ 384
#define H_ 12
#define PQ_ 8
#define PV_ 12
#define PKV_ 20
#define CQ_ (H_*PQ_*3)    // 288
#define CKV_ (H_*PKV_*3)  // 720
#define INF_ 100000.0f
#define HW_SCALE_ 0.09622504486493764f   // sqrt(1/108)
#define LOG2E_ 1.4426950408889634f

typedef __attribute__((ext_vector_type(8))) short bf16x8;
typedef __attribute__((ext_vector_type(4))) float f32x4;

__device__ inline unsigned short f2bf(float x) {
  unsigned u = __float_as_uint(x);
  u += 0x7fffu + ((u >> 16) & 1u);      // RNE
  return (unsigned short)(u >> 16);
}

// convert 8 consecutive f32 -> bf16x8 fragment (two dwordx4 loads)
__device__ inline bf16x8 cvt8(const float* __restrict__ p) {
  float4 a = *(const float4*)p;
  float4 b = *(const float4*)(p + 4);
  bf16x8 r;
  r[0] = (short)f2bf(a.x); r[1] = (short)f2bf(a.y);
  r[2] = (short)f2bf(a.z); r[3] = (short)f2bf(a.w);
  r[4] = (short)f2bf(b.x); r[5] = (short)f2bf(b.y);
  r[6] = (short)f2bf(b.z); r[7] = (short)f2bf(b.w);
  return r;
}

// ---------------- prep: weight transposes + vtb pad + kn zero ----------------
#define TQ_   108   // Wq  384x288: 12 k-tiles x 9 n-tiles
#define TKV_  276   // Wkv 384x720: 12 x 23 (guard n<720)
#define TWO_  216   // Wout 576x384: 18 x 12
#define VPAD_ 72    // vtb comps 36..47 = 0 (147456 elts, 8/thr)
#define KN_   12    // kn = 0 (12288 f32, 4/thr)
#define PREP_GRID_ (TQ_+TKV_+TWO_+VPAD_+KN_)
__global__ __launch_bounds__(256) void prep_kernel(
    const float* __restrict__ Wq, const float* __restrict__ Wkv,
    const float* __restrict__ Wout,
    unsigned short* __restrict__ wqT, unsigned short* __restrict__ wkvT,
    unsigned short* __restrict__ woutT,
    unsigned short* __restrict__ vtb, float* __restrict__ kn)
{
  __shared__ float lds[32][33];
  int blk = blockIdx.x, t = threadIdx.x;
  int rr0 = t >> 5, cc = t & 31;

  const float* src = nullptr; unsigned short* dst = nullptr;
  int K = 0, N = 0, k0 = 0, n0 = 0;
  if (blk < TQ_) {
    src = Wq; dst = wqT; K = 384; N = CQ_;
    k0 = (blk % 12) * 32; n0 = (blk / 12) * 32;
  } else if (blk < TQ_ + TKV_) {
    int b2 = blk - TQ_;
    src = Wkv; dst = wkvT; K = 384; N = CKV_;
    k0 = (b2 % 12) * 32; n0 = (b2 / 12) * 32;
  } else if (blk < TQ_ + TKV_ + TWO_) {
    int b3 = blk - TQ_ - TKV_;
    src = Wout; dst = woutT; K = 576; N = CS_;
    k0 = (b3 % 18) * 32; n0 = (b3 / 18) * 32;
  } else if (blk < TQ_ + TKV_ + TWO_ + VPAD_) {
    int idx = (blk - TQ_ - TKV_ - TWO_)*256 + t;
    int f = idx * 8;
    int run = f >> 9, off = f & 511;
    int bh = run / 12, cc2 = 36 + run % 12;
    uint4 z = {0u,0u,0u,0u};
    *(uint4*)(vtb + ((size_t)bh*48 + cc2)*512 + off) = z;
    return;
  } else {
    int idx = (blk - TQ_ - TKV_ - TWO_ - VPAD_)*256 + t;
    float4 z = {0.f,0.f,0.f,0.f};
    *(float4*)(kn + (size_t)idx*4) = z;
    return;
  }

  #pragma unroll
  for (int rr = 0; rr < 4; ++rr) {
    int r = rr0 + rr*8;
    if (n0 + cc < N) lds[r][cc] = src[(size_t)(k0 + r)*N + n0 + cc];
  }
  __syncthreads();
  #pragma unroll
  for (int rr = 0; rr < 4; ++rr) {
    int r = rr0 + rr*8;
    if (n0 + r < N) dst[(size_t)(n0 + r)*K + k0 + cc] = f2bf(lds[cc][r]);
  }
}

// ---------------- fused Q + KV projection via MFMA, 2-way k-split ----------------
// 624 blocks x 512 thr (8 waves = 4 pair-slots x 2 k-halves). Blocks [0,384): Q
// (pair ids 0..1535); [384,624): KV (0..959). kh=1 wave stashes its 12 partial
// accs in LDS; kh=0 wave merges and runs the epilogue. A-operand read directly
// from f32 s1/s2 with inline cvt8 (no pre-converted bf16 copy).
__global__ __launch_bounds__(512) void proj_mfma(
    const float* __restrict__ s1, const float* __restrict__ s2,
    const unsigned short* __restrict__ wqT, const unsigned short* __restrict__ wkvT,
    const float* __restrict__ r1_rot, const float* __restrict__ r1_trans,
    const float* __restrict__ r2_rot, const float* __restrict__ r2_trans,
    unsigned short* __restrict__ qgb, float* __restrict__ qn,
    unsigned short* __restrict__ kgb, unsigned short* __restrict__ vtb,
    float* __restrict__ kn)
{
  __shared__ float merge_s[4][64][13];   // stride 13: gcd(13,32)=1, conflict-free
  int wave = threadIdx.x >> 6, lane = threadIdx.x & 63;
  int col = lane & 15, g = lane >> 4;
  int pr = wave >> 1, kh = wave & 1;
  int k0 = kh * 192;

  if (blockIdx.x < 384) {
    // ---- Q projection ----
    int pid = blockIdx.x*4 + pr;         // 0..1535
    int strip = pid / 6;                 // 0..255
    int nt = pid % 6;
    int i0 = strip * 16;

    f32x4 ax = {0.f,0.f,0.f,0.f}, ay = ax, az = ax;
    const float* arow = s1 + (size_t)(i0 + col)*CS_ + k0;
    const unsigned short* bx = wqT + (size_t)((nt     )*16 + col)*CS_ + k0;
    const unsigned short* by = wqT + (size_t)((nt +  6)*16 + col)*CS_ + k0;
    const unsigned short* bz = wqT + (size_t)((nt + 12)*16 + col)*CS_ + k0;
    #pragma unroll
    for (int k = 0; k < 192; k += 32) {
      bf16x8 a = cvt8(arow + k + g*8);
      ax = __builtin_amdgcn_mfma_f32_16x16x32_bf16(a, *(const bf16x8*)(bx + k + g*8), ax, 0,0,0);
      ay = __builtin_amdgcn_mfma_f32_16x16x32_bf16(a, *(const bf16x8*)(by + k + g*8), ay, 0,0,0);
      az = __builtin_amdgcn_mfma_f32_16x16x32_bf16(a, *(const bf16x8*)(bz + k + g*8), az, 0,0,0);
    }
    if (kh) {
      #pragma unroll
      for (int r = 0; r < 4; ++r) {
        merge_s[pr][lane][r]     = ax[r];
        merge_s[pr][lane][4 + r] = ay[r];
        merge_s[pr][lane][8 + r] = az[r];
      }
    }
    __syncthreads();
    if (kh) return;
    #pragma unroll
    for (int r = 0; r < 4; ++r) {
      ax[r] += merge_s[pr][lane][r];
      ay[r] += merge_s[pr][lane][4 + r];
      az[r] += merge_s[pr][lane][8 + r];
    }

    int p = nt*16 + col;
    int h = p >> 3, pq = p & 7;
    float qsum[4];
    #pragma unroll
    for (int r = 0; r < 4; ++r) {
      int row = i0 + g*4 + r;
      const float* R  = r1_rot   + (size_t)row*9;
      const float* tr = r1_trans + (size_t)row*3;
      float x = ax[r], y = ay[r], z = az[r];
      float g0 = R[0]*x + R[1]*y + R[2]*z + tr[0];
      float g1 = R[3]*x + R[4]*y + R[5]*z + tr[1];
      float g2 = R[6]*x + R[7]*y + R[8]*z + tr[2];
      int b = row >> 11, i = row & (N1_-1);
      size_t rbase = ((size_t)(b*H_ + h)*N1_ + i)*32;
      qgb[rbase + pq*3]     = f2bf(g0);
      qgb[rbase + pq*3 + 1] = f2bf(g1);
      qgb[rbase + pq*3 + 2] = f2bf(g2);
      if (pq == 7) {
        uint4 z4 = {0u,0u,0u,0u};
        *(uint4*)(qgb + rbase + 24) = z4;
      }
      qsum[r] = g0*g0 + g1*g1 + g2*g2;
    }
    #pragma unroll
    for (int r = 0; r < 4; ++r) {
      qsum[r] += __shfl_xor(qsum[r], 1);
      qsum[r] += __shfl_xor(qsum[r], 2);
      qsum[r] += __shfl_xor(qsum[r], 4);
    }
    if ((col & 7) == 0) {
      int hh = nt*2 + (col >> 3);
      #pragma unroll
      for (int r = 0; r < 4; ++r) {
        int row = i0 + g*4 + r;
        int b = row >> 11, i = row & (N1_-1);
        qn[(size_t)(b*H_ + hh)*N1_ + i] = qsum[r];
      }
    }
  } else {
    // ---- KV projection ----
    int pid = (blockIdx.x - 384)*4 + pr;   // 0..959
    int strip = pid / 15;                  // 0..63
    int nt = pid % 15;                     // 0..14
    int row0 = strip * 16;

    f32x4 ax = {0.f,0.f,0.f,0.f}, ay = ax, az = ax;
    const float* arow = s2 + (size_t)(row0 + col)*CS_ + k0;
    const unsigned short* bx = wkvT + (size_t)(nt*16       + col)*CS_ + k0;
    const unsigned short* by = wkvT + (size_t)(nt*16 + 240 + col)*CS_ + k0;
    const unsigned short* bz = wkvT + (size_t)(nt*16 + 480 + col)*CS_ + k0;
    #pragma unroll
    for (int k = 0; k < 192; k += 32) {
      bf16x8 a = cvt8(arow + k + g*8);
      ax = __builtin_amdgcn_mfma_f32_16x16x32_bf16(a, *(const bf16x8*)(bx + k + g*8), ax, 0,0,0);
      ay = __builtin_amdgcn_mfma_f32_16x16x32_bf16(a, *(const bf16x8*)(by + k + g*8), ay, 0,0,0);
      az = __builtin_amdgcn_mfma_f32_16x16x32_bf16(a, *(const bf16x8*)(bz + k + g*8), az, 0,0,0);
    }
    if (kh) {
      #pragma unroll
      for (int r = 0; r < 4; ++r) {
        merge_s[pr][lane][r]     = ax[r];
        merge_s[pr][lane][4 + r] = ay[r];
        merge_s[pr][lane][8 + r] = az[r];
      }
    }
    __syncthreads();
    if (kh) return;
    #pragma unroll
    for (int r = 0; r < 4; ++r) {
      ax[r] += merge_s[pr][lane][r];
      ay[r] += merge_s[pr][lane][4 + r];
      az[r] += merge_s[pr][lane][8 + r];
    }

    int p = nt*16 + col;
    int h = p / PKV_, pp = p % PKV_;
    #pragma unroll
    for (int r = 0; r < 4; ++r) {
      int row = row0 + g*4 + r;
      const float* R  = r2_rot   + (size_t)row*9;
      const float* tr = r2_trans + (size_t)row*3;
      float x = ax[r], y = ay[r], z = az[r];
      float g0 = R[0]*x + R[1]*y + R[2]*z + tr[0];
      float g1 = R[3]*x + R[4]*y + R[5]*z + tr[1];
      float g2 = R[6]*x + R[7]*y + R[8]*z + tr[2];
      int b = row >> 9, j = row & (N2_-1);
      int bh = b*H_ + h;
      if (pp < PQ_) {
        size_t base = ((size_t)bh*N2_ + j)*32 + pp*3;
        kgb[base]   = f2bf(g0);
        kgb[base+1] = f2bf(g1);
        kgb[base+2] = f2bf(g2);
        if (pp == 0) {
          uint4 z4 = {0u,0u,0u,0u};
          *(uint4*)(kgb + ((size_t)bh*N2_ + j)*32 + 24) = z4;
        }
        atomicAdd(&kn[(size_t)bh*N2_ + j], g0*g0 + g1*g1 + g2*g2);
      } else {
        int comp = (pp - PQ_)*3;
        size_t base = ((size_t)bh*48 + comp)*512 + j;
        vtb[base]        = f2bf(g0);
        vtb[base + 512]  = f2bf(g1);
        vtb[base + 1024] = f2bf(g2);
      }
    }
  }
}

// ---------------- fused MFMA flash attention + output projection ----------------
// Round-3 structure (best measured: 43.4 us): one block per (b, i-tile of 16
// rows), 12 waves = 12 heads, full j-sweep per wave, 1-deep register prefetch.
// Added: s_setprio(1/0) around the PV MFMA cluster (T5 — independent waves).
#define RSTRIDE 72
#define OSTRIDE 51
#define WSLOT 3328          // max(16*72*2, 16*51*4) rounded to 16B; pstrip/o_s overlay
#define FSTRIDE 584         // 576 + 8 bf16 pad -> 16B-offset per row, conflict-free b128
__global__ __launch_bounds__(768, 3) void attn_fused(
    const unsigned short* __restrict__ qgb, const float* __restrict__ qn,
    const unsigned short* __restrict__ kgb, const unsigned short* __restrict__ vtb,
    const float* __restrict__ kn, const float* __restrict__ mask1,
    const float* __restrict__ mask2, const float* __restrict__ hwts,
    const float* __restrict__ rot, const float* __restrict__ trans,
    const unsigned short* __restrict__ woutT, const float* __restrict__ bout,
    float* __restrict__ out)
{
  __shared__ __align__(16) unsigned char ovl[12*WSLOT];          // 39936 B
  __shared__ __align__(16) unsigned short feats_s[16][FSTRIDE];  // 18688 B
  __shared__ float l_s[12][16];                                  // 768 B

  int wave = threadIdx.x >> 6;
  int lane = threadIdx.x & 63;
  int col = lane & 15, g = lane >> 4;
  int b = blockIdx.x >> 7;
  int it = blockIdx.x & 127;
  int h = wave;
  int bh = b*H_ + h;

  unsigned short* ps = (unsigned short*)(ovl + wave*WSLOT);  // [16][RSTRIDE] u16
  float*          os = (float*)(ovl + wave*WSLOT);           // [16][OSTRIDE] f32 (after last ps use)

  float hw   = logf(1.0f + __expf(hwts[h])) * HW_SCALE_;
  float hwl  = hw * LOG2E_;                 // log2-domain scale
  float mneg = -INF_ * LOG2E_;

  bf16x8 qa = *(const bf16x8*)(qgb + (((size_t)bh*N1_ + it*16 + col)*32 + g*8));

  float ar[4], m1l[4];
  #pragma unroll
  for (int r = 0; r < 4; ++r) {
    int ig = it*16 + g*4 + r;
    ar[r]  = -0.5f*hwl * qn[(size_t)bh*N1_ + ig];
    m1l[r] = mask1[b*N1_ + ig] * (INF_*LOG2E_);   // fma(m1l, m2, mneg) == 0 exactly when unmasked
  }

  f32x4 ot[3];
  #pragma unroll
  for (int m = 0; m < 3; ++m) ot[m] = (f32x4){0.f,0.f,0.f,0.f};
  float l[4] = {0.f,0.f,0.f,0.f};

  const unsigned short* kbase = kgb + (size_t)bh*N2_*32;
  const unsigned short* vbase = vtb + (size_t)bh*48*512;
  const float* knp = kn + (size_t)bh*N2_;
  const float* m2p = mask2 + b*N2_;

  // ---- software pipeline: register-prefetch next j-tile's K/V/scalars ----
  bf16x8 kbuf[4], vbuf[6];
  float knb[4], m2b[4];
  #pragma unroll
  for (int nt = 0; nt < 4; ++nt) {
    int jg = nt*16 + col;
    kbuf[nt] = *(const bf16x8*)(kbase + ((size_t)jg*32 + g*8));
    knb[nt] = knp[jg];
    m2b[nt] = m2p[jg];
  }
  #pragma unroll
  for (int ks = 0; ks < 2; ++ks)
    #pragma unroll
    for (int mtv = 0; mtv < 3; ++mtv)
      vbuf[ks*3 + mtv] = *(const bf16x8*)(vbase +
          ((size_t)(mtv*16 + col))*512 + ks*32 + g*8);

  for (int jt = 0; jt < 8; ++jt) {
    int j0 = jt*64;
    bf16x8 kNx[4], vNx[6];
    float knN[4], m2N[4];
    if (jt < 7) {
      int j1 = j0 + 64;
      #pragma unroll
      for (int nt = 0; nt < 4; ++nt) {
        int jg = j1 + nt*16 + col;
        kNx[nt] = *(const bf16x8*)(kbase + ((size_t)jg*32 + g*8));
        knN[nt] = knp[jg];
        m2N[nt] = m2p[jg];
      }
      #pragma unroll
      for (int ks = 0; ks < 2; ++ks)
        #pragma unroll
        for (int mtv = 0; mtv < 3; ++mtv)
          vNx[ks*3 + mtv] = *(const bf16x8*)(vbase +
              ((size_t)(mtv*16 + col))*512 + j1 + ks*32 + g*8);
    }

    #pragma unroll
    for (int nt = 0; nt < 4; ++nt) {
      f32x4 dotv = __builtin_amdgcn_mfma_f32_16x16x32_bf16(
          qa, kbuf[nt], (f32x4){0.f,0.f,0.f,0.f}, 0, 0, 0);
      float bc  = -0.5f*hwl*knb[nt];
      float m2c = m2b[nt];
      #pragma unroll
      for (int r = 0; r < 4; ++r) {
        float logit = fmaf(hwl, dotv[r], fmaf(m1l[r], m2c, mneg) + (ar[r] + bc));
        float w = __builtin_amdgcn_exp2f(logit);   // logit <= 0 -> w <= 1
        l[r] += w;
        ps[(g*4 + r)*RSTRIDE + nt*16 + col] = f2bf(w);
      }
    }
    __builtin_amdgcn_s_setprio(1);
    #pragma unroll
    for (int ks = 0; ks < 2; ++ks) {
      bf16x8 pb = *(const bf16x8*)&ps[col*RSTRIDE + ks*32 + g*8];
      #pragma unroll
      for (int mtv = 0; mtv < 3; ++mtv)
        ot[mtv] = __builtin_amdgcn_mfma_f32_16x16x32_bf16(vbuf[ks*3 + mtv], pb, ot[mtv], 0, 0, 0);
    }
    __builtin_amdgcn_s_setprio(0);

    if (jt < 7) {
      #pragma unroll
      for (int i = 0; i < 4; ++i) { kbuf[i] = kNx[i]; knb[i] = knN[i]; m2b[i] = m2N[i]; }
      #pragma unroll
      for (int i = 0; i < 6; ++i) vbuf[i] = vNx[i];
    }
  }

  // reduce l over the 16 cols; stash l and O partials in LDS
  #pragma unroll
  for (int r = 0; r < 4; ++r) {
    l[r] += __shfl_xor(l[r], 1);
    l[r] += __shfl_xor(l[r], 2);
    l[r] += __shfl_xor(l[r], 4);
    l[r] += __shfl_xor(l[r], 8);
  }
  __builtin_amdgcn_sched_barrier(0);   // keep os writes after the final ps reads
  if (col == 0) {
    #pragma unroll
    for (int r = 0; r < 4; ++r) l_s[wave][g*4 + r] = l[r];
  }
  #pragma unroll
  for (int mtv = 0; mtv < 3; ++mtv)
    #pragma unroll
    for (int r = 0; r < 4; ++r)
      os[col*OSTRIDE + mtv*16 + g*4 + r] = ot[mtv][r];
  __syncthreads();

  // epilogue: rotate back to local frame, write bf16 feats slice to LDS
  {
    float inv = 1.0f / l_s[wave][col];
    int ig = it*16 + col;
    int row = b*N1_ + ig;
    const float* R  = rot   + (size_t)row*9;
    const float* tr = trans + (size_t)row*3;
    float R00=R[0],R01=R[1],R02=R[2],R10=R[3],R11=R[4],R12=R[5],R20=R[6],R21=R[7],R22=R[8];
    float t0=tr[0], t1=tr[1], t2=tr[2];
    int h12 = h*PV_;
    #pragma unroll
    for (int p = 0; p < 3; ++p) {
      int pt = g*3 + p;
      float ox = os[col*OSTRIDE + pt*3+0]*inv - t0;
      float oy = os[col*OSTRIDE + pt*3+1]*inv - t1;
      float oz = os[col*OSTRIDE + pt*3+2]*inv - t2;
      float lx = R00*ox + R10*oy + R20*oz;
      float ly = R01*ox + R11*oy + R21*oz;
      float lz = R02*ox + R12*oy + R22*oz;
      float dist = sqrtf(lx*lx + ly*ly + lz*lz + 1e-8f);
      feats_s[col][      h12 + pt] = f2bf(lx);
      feats_s[col][144 + h12 + pt] = f2bf(ly);
      feats_s[col][288 + h12 + pt] = f2bf(lz);
      feats_s[col][432 + h12 + pt] = f2bf(dist);
    }
  }
  __syncthreads();

  // output projection: wave handles cols [wave*32, wave*32+32) of out
  {
    int n0 = wave * 32;
    f32x4 acc0 = {0.f,0.f,0.f,0.f}, acc1 = acc0;
    const unsigned short* b0 = woutT + (size_t)(n0      + col)*576;
    const unsigned short* b1 = woutT + (size_t)(n0 + 16 + col)*576;
    #pragma unroll 3
    for (int k = 0; k < 576; k += 32) {
      bf16x8 a = *(const bf16x8*)&feats_s[col][k + g*8];
      acc0 = __builtin_amdgcn_mfma_f32_16x16x32_bf16(a, *(const bf16x8*)(b0 + k + g*8), acc0, 0,0,0);
      acc1 = __builtin_amdgcn_mfma_f32_16x16x32_bf16(a, *(const bf16x8*)(b1 + k + g*8), acc1, 0,0,0);
    }
    int rowbase = b*N1_ + it*16;
    float bb0 = bout[n0 + col];
    float bb1 = bout[n0 + 16 + col];
    #pragma unroll
    for (int r = 0; r < 4; ++r) {
      size_t orow = (size_t)(rowbase + g*4 + r)*CS_;
      out[orow + n0 + col]      = acc0[r] + bb0;
      out[orow + n0 + 16 + col] = acc1[r] + bb1;
    }
  }
}

extern "C" void kernel_launch(void* const* d_in, const int* in_sizes, int n_in,
                              void* d_out, int out_size, void* d_ws, size_t ws_size,
                              hipStream_t stream) {
  const float* s1       = (const float*)d_in[0];
  const float* s2       = (const float*)d_in[1];
  const float* r1_rot   = (const float*)d_in[2];
  const float* r1_trans = (const float*)d_in[3];
  const float* r2_rot   = (const float*)d_in[4];
  const float* r2_trans = (const float*)d_in[5];
  const float* mask1    = (const float*)d_in[6];
  const float* mask2    = (const float*)d_in[7];
  const float* Wq       = (const float*)d_in[8];
  const float* Wkv      = (const float*)d_in[9];
  const float* hwts     = (const float*)d_in[10];
  const float* Wout     = (const float*)d_in[11];
  const float* bout     = (const float*)d_in[12];
  float* out = (float*)d_out;

  float* qn = (float*)d_ws;                              // 49152 f32
  float* kn = qn + (size_t)B_*H_*N1_;                    // 12288 f32
  unsigned short* qgb  = (unsigned short*)(kn + (size_t)B_*H_*N2_); // 1572864 u16
  unsigned short* kgb  = qgb  + (size_t)B_*H_*N1_*32;    // 393216 u16
  unsigned short* vtb  = kgb  + (size_t)B_*H_*N2_*32;    // 589824 u16
  unsigned short* wqT  = vtb  + (size_t)B_*H_*48*512;    // 110592 u16
  unsigned short* wkvT = wqT  + (size_t)CQ_*CS_;         // 276480 u16
  unsigned short* woutT= wkvT + (size_t)CKV_*CS_;        // 221184 u16

  prep_kernel<<<PREP_GRID_, 256, 0, stream>>>(
      Wq, Wkv, Wout, wqT, wkvT, woutT, vtb, kn);
  proj_mfma<<<624, 512, 0, stream>>>(s1, s2, wqT, wkvT, r1_rot, r1_trans,
                                     r2_rot, r2_trans, qgb, qn, kgb, vtb, kn);
  attn_fused<<<B_*(N1_/16), 768, 0, stream>>>(qgb, qn, kgb, vtb, kn, mask1, mask2,
                                              hwts, r1_rot, r1_trans, woutT, bout, out);
}

// Round 8
// 151.061 us; speedup vs baseline: 1.4890x; 1.0066x over previous
//
#include <hip/hip_runtime.h>
#include <math.h>

#define B_ 2
#define N1_ 2048
#define N2_ 512
#define CS_ 384
#define H_ 12
#define PQ_ 8
#define PV_ 12
#define PKV_ 20
#define CQ_ (H_*PQ_*3)    // 288
#define CKV_ (H_*PKV_*3)  // 720
#define INF_ 100000.0f
#define HW_SCALE_ 0.09622504486493764f   // sqrt(1/108)
#define LOG2E_ 1.4426950408889634f

typedef __attribute__((ext_vector_type(8))) short bf16x8;
typedef __attribute__((ext_vector_type(4))) float f32x4;
typedef __attribute__((ext_vector_type(4))) unsigned int u32x4;

__device__ inline unsigned short f2bf(float x) {
  unsigned u = __float_as_uint(x);
  u += 0x7fffu + ((u >> 16) & 1u);      // RNE
  return (unsigned short)(u >> 16);
}

// pack two f32 -> one dword of 2 bf16 (RNE), single instruction
__device__ inline unsigned cvtpk_bf16(float lo, float hi) {
  unsigned d;
  asm("v_cvt_pk_bf16_f32 %0, %1, %2" : "=v"(d) : "v"(lo), "v"(hi));
  return d;
}

// convert 8 consecutive f32 -> bf16x8 fragment (two dwordx4 loads)
__device__ inline bf16x8 cvt8(const float* __restrict__ p) {
  float4 a = *(const float4*)p;
  float4 b = *(const float4*)(p + 4);
  bf16x8 r;
  r[0] = (short)f2bf(a.x); r[1] = (short)f2bf(a.y);
  r[2] = (short)f2bf(a.z); r[3] = (short)f2bf(a.w);
  r[4] = (short)f2bf(b.x); r[5] = (short)f2bf(b.y);
  r[6] = (short)f2bf(b.z); r[7] = (short)f2bf(b.w);
  return r;
}

// ---------------- prep: weight transposes + vtb pad + kn zero + s1/s2 -> bf16 ----------------
#define TQ_   108   // Wq  384x288: 12 k-tiles x 9 n-tiles
#define TKV_  276   // Wkv 384x720: 12 x 23 (guard n<720)
#define TWO_  216   // Wout 576x384: 18 x 12
#define VPAD_ 72    // vtb comps 36..47 = 0 (147456 elts, 8/thr)
#define KN_   12    // kn = 0 (12288 f32, 4/thr)
#define S1B_  768   // s1 -> bf16 (1572864 elts, 8/thr)
#define S2B_  192   // s2 -> bf16 (393216 elts, 8/thr)
#define PREP_GRID_ (TQ_+TKV_+TWO_+VPAD_+KN_+S1B_+S2B_)
__global__ __launch_bounds__(256) void prep_kernel(
    const float* __restrict__ Wq, const float* __restrict__ Wkv,
    const float* __restrict__ Wout,
    const float* __restrict__ s1, const float* __restrict__ s2,
    unsigned short* __restrict__ wqT, unsigned short* __restrict__ wkvT,
    unsigned short* __restrict__ woutT,
    unsigned short* __restrict__ vtb, float* __restrict__ kn,
    unsigned short* __restrict__ s1b, unsigned short* __restrict__ s2b)
{
  __shared__ float lds[32][33];
  int blk = blockIdx.x, t = threadIdx.x;
  int rr0 = t >> 5, cc = t & 31;

  const float* src = nullptr; unsigned short* dst = nullptr;
  int K = 0, N = 0, k0 = 0, n0 = 0;
  if (blk < TQ_) {
    src = Wq; dst = wqT; K = 384; N = CQ_;
    k0 = (blk % 12) * 32; n0 = (blk / 12) * 32;
  } else if (blk < TQ_ + TKV_) {
    int b2 = blk - TQ_;
    src = Wkv; dst = wkvT; K = 384; N = CKV_;
    k0 = (b2 % 12) * 32; n0 = (b2 / 12) * 32;
  } else if (blk < TQ_ + TKV_ + TWO_) {
    int b3 = blk - TQ_ - TKV_;
    src = Wout; dst = woutT; K = 576; N = CS_;
    k0 = (b3 % 18) * 32; n0 = (b3 / 18) * 32;
  } else if (blk < TQ_ + TKV_ + TWO_ + VPAD_) {
    int idx = (blk - TQ_ - TKV_ - TWO_)*256 + t;
    int f = idx * 8;
    int run = f >> 9, off = f & 511;
    int bh = run / 12, cc2 = 36 + run % 12;
    uint4 z = {0u,0u,0u,0u};
    *(uint4*)(vtb + ((size_t)bh*48 + cc2)*512 + off) = z;
    return;
  } else if (blk < TQ_ + TKV_ + TWO_ + VPAD_ + KN_) {
    int idx = (blk - TQ_ - TKV_ - TWO_ - VPAD_)*256 + t;
    float4 z = {0.f,0.f,0.f,0.f};
    *(float4*)(kn + (size_t)idx*4) = z;
    return;
  } else if (blk < TQ_ + TKV_ + TWO_ + VPAD_ + KN_ + S1B_) {
    size_t idx = (size_t)(blk - TQ_ - TKV_ - TWO_ - VPAD_ - KN_)*256 + t;
    *(bf16x8*)(s1b + idx*8) = cvt8(s1 + idx*8);
    return;
  } else {
    size_t idx = (size_t)(blk - TQ_ - TKV_ - TWO_ - VPAD_ - KN_ - S1B_)*256 + t;
    *(bf16x8*)(s2b + idx*8) = cvt8(s2 + idx*8);
    return;
  }

  #pragma unroll
  for (int rr = 0; rr < 4; ++rr) {
    int r = rr0 + rr*8;
    if (n0 + cc < N) lds[r][cc] = src[(size_t)(k0 + r)*N + n0 + cc];
  }
  __syncthreads();
  #pragma unroll
  for (int rr = 0; rr < 4; ++rr) {
    int r = rr0 + rr*8;
    if (n0 + r < N) dst[(size_t)(n0 + r)*K + k0 + cc] = f2bf(lds[cc][r]);
  }
}

// ---------------- fused Q + KV projection via MFMA, 2-way k-split ----------------
// 624 blocks x 512 thr (8 waves = 4 pair-slots x 2 k-halves). Blocks [0,384): Q
// (pair ids 0..1535); [384,624): KV (0..959). kh=1 wave stashes its 12 partial
// accs in LDS; kh=0 wave merges and runs the epilogue.
__global__ __launch_bounds__(512) void proj_mfma(
    const unsigned short* __restrict__ s1b, const unsigned short* __restrict__ s2b,
    const unsigned short* __restrict__ wqT, const unsigned short* __restrict__ wkvT,
    const float* __restrict__ r1_rot, const float* __restrict__ r1_trans,
    const float* __restrict__ r2_rot, const float* __restrict__ r2_trans,
    unsigned short* __restrict__ qgb, float* __restrict__ qn,
    unsigned short* __restrict__ kgb, unsigned short* __restrict__ vtb,
    float* __restrict__ kn)
{
  __shared__ float merge_s[4][64][13];   // stride 13: gcd(13,32)=1, conflict-free
  int wave = threadIdx.x >> 6, lane = threadIdx.x & 63;
  int col = lane & 15, g = lane >> 4;
  int pr = wave >> 1, kh = wave & 1;
  int k0 = kh * 192;

  if (blockIdx.x < 384) {
    // ---- Q projection ----
    int pid = blockIdx.x*4 + pr;         // 0..1535
    int strip = pid / 6;                 // 0..255
    int nt = pid % 6;
    int i0 = strip * 16;

    f32x4 ax = {0.f,0.f,0.f,0.f}, ay = ax, az = ax;
    const unsigned short* arow = s1b + (size_t)(i0 + col)*CS_ + k0;
    const unsigned short* bx = wqT + (size_t)((nt     )*16 + col)*CS_ + k0;
    const unsigned short* by = wqT + (size_t)((nt +  6)*16 + col)*CS_ + k0;
    const unsigned short* bz = wqT + (size_t)((nt + 12)*16 + col)*CS_ + k0;
    #pragma unroll
    for (int k = 0; k < 192; k += 32) {
      bf16x8 a = *(const bf16x8*)(arow + k + g*8);
      ax = __builtin_amdgcn_mfma_f32_16x16x32_bf16(a, *(const bf16x8*)(bx + k + g*8), ax, 0,0,0);
      ay = __builtin_amdgcn_mfma_f32_16x16x32_bf16(a, *(const bf16x8*)(by + k + g*8), ay, 0,0,0);
      az = __builtin_amdgcn_mfma_f32_16x16x32_bf16(a, *(const bf16x8*)(bz + k + g*8), az, 0,0,0);
    }
    if (kh) {
      #pragma unroll
      for (int r = 0; r < 4; ++r) {
        merge_s[pr][lane][r]     = ax[r];
        merge_s[pr][lane][4 + r] = ay[r];
        merge_s[pr][lane][8 + r] = az[r];
      }
    }
    __syncthreads();
    if (kh) return;
    #pragma unroll
    for (int r = 0; r < 4; ++r) {
      ax[r] += merge_s[pr][lane][r];
      ay[r] += merge_s[pr][lane][4 + r];
      az[r] += merge_s[pr][lane][8 + r];
    }

    int p = nt*16 + col;
    int h = p >> 3, pq = p & 7;
    float qsum[4];
    #pragma unroll
    for (int r = 0; r < 4; ++r) {
      int row = i0 + g*4 + r;
      const float* R  = r1_rot   + (size_t)row*9;
      const float* tr = r1_trans + (size_t)row*3;
      float x = ax[r], y = ay[r], z = az[r];
      float g0 = R[0]*x + R[1]*y + R[2]*z + tr[0];
      float g1 = R[3]*x + R[4]*y + R[5]*z + tr[1];
      float g2 = R[6]*x + R[7]*y + R[8]*z + tr[2];
      int b = row >> 11, i = row & (N1_-1);
      size_t rbase = ((size_t)(b*H_ + h)*N1_ + i)*32;
      qgb[rbase + pq*3]     = f2bf(g0);
      qgb[rbase + pq*3 + 1] = f2bf(g1);
      qgb[rbase + pq*3 + 2] = f2bf(g2);
      if (pq == 7) {
        uint4 z4 = {0u,0u,0u,0u};
        *(uint4*)(qgb + rbase + 24) = z4;
      }
      qsum[r] = g0*g0 + g1*g1 + g2*g2;
    }
    #pragma unroll
    for (int r = 0; r < 4; ++r) {
      qsum[r] += __shfl_xor(qsum[r], 1);
      qsum[r] += __shfl_xor(qsum[r], 2);
      qsum[r] += __shfl_xor(qsum[r], 4);
    }
    if ((col & 7) == 0) {
      int hh = nt*2 + (col >> 3);
      #pragma unroll
      for (int r = 0; r < 4; ++r) {
        int row = i0 + g*4 + r;
        int b = row >> 11, i = row & (N1_-1);
        qn[(size_t)(b*H_ + hh)*N1_ + i] = qsum[r];
      }
    }
  } else {
    // ---- KV projection ----
    int pid = (blockIdx.x - 384)*4 + pr;   // 0..959
    int strip = pid / 15;                  // 0..63
    int nt = pid % 15;                     // 0..14
    int row0 = strip * 16;

    f32x4 ax = {0.f,0.f,0.f,0.f}, ay = ax, az = ax;
    const unsigned short* arow = s2b + (size_t)(row0 + col)*CS_ + k0;
    const unsigned short* bx = wkvT + (size_t)(nt*16       + col)*CS_ + k0;
    const unsigned short* by = wkvT + (size_t)(nt*16 + 240 + col)*CS_ + k0;
    const unsigned short* bz = wkvT + (size_t)(nt*16 + 480 + col)*CS_ + k0;
    #pragma unroll
    for (int k = 0; k < 192; k += 32) {
      bf16x8 a = *(const bf16x8*)(arow + k + g*8);
      ax = __builtin_amdgcn_mfma_f32_16x16x32_bf16(a, *(const bf16x8*)(bx + k + g*8), ax, 0,0,0);
      ay = __builtin_amdgcn_mfma_f32_16x16x32_bf16(a, *(const bf16x8*)(by + k + g*8), ay, 0,0,0);
      az = __builtin_amdgcn_mfma_f32_16x16x32_bf16(a, *(const bf16x8*)(bz + k + g*8), az, 0,0,0);
    }
    if (kh) {
      #pragma unroll
      for (int r = 0; r < 4; ++r) {
        merge_s[pr][lane][r]     = ax[r];
        merge_s[pr][lane][4 + r] = ay[r];
        merge_s[pr][lane][8 + r] = az[r];
      }
    }
    __syncthreads();
    if (kh) return;
    #pragma unroll
    for (int r = 0; r < 4; ++r) {
      ax[r] += merge_s[pr][lane][r];
      ay[r] += merge_s[pr][lane][4 + r];
      az[r] += merge_s[pr][lane][8 + r];
    }

    int p = nt*16 + col;
    int h = p / PKV_, pp = p % PKV_;
    #pragma unroll
    for (int r = 0; r < 4; ++r) {
      int row = row0 + g*4 + r;
      const float* R  = r2_rot   + (size_t)row*9;
      const float* tr = r2_trans + (size_t)row*3;
      float x = ax[r], y = ay[r], z = az[r];
      float g0 = R[0]*x + R[1]*y + R[2]*z + tr[0];
      float g1 = R[3]*x + R[4]*y + R[5]*z + tr[1];
      float g2 = R[6]*x + R[7]*y + R[8]*z + tr[2];
      int b = row >> 9, j = row & (N2_-1);
      int bh = b*H_ + h;
      if (pp < PQ_) {
        size_t base = ((size_t)bh*N2_ + j)*32 + pp*3;
        kgb[base]   = f2bf(g0);
        kgb[base+1] = f2bf(g1);
        kgb[base+2] = f2bf(g2);
        if (pp == 0) {
          uint4 z4 = {0u,0u,0u,0u};
          *(uint4*)(kgb + ((size_t)bh*N2_ + j)*32 + 24) = z4;
        }
        atomicAdd(&kn[(size_t)bh*N2_ + j], g0*g0 + g1*g1 + g2*g2);
      } else {
        int comp = (pp - PQ_)*3;
        size_t base = ((size_t)bh*48 + comp)*512 + j;
        vtb[base]        = f2bf(g0);
        vtb[base + 512]  = f2bf(g1);
        vtb[base + 1024] = f2bf(g2);
      }
    }
  }
}

// ---------------- fused MFMA flash attention + output projection ----------------
// Swapped-QK instruction diet: mfma(K,Q) puts S with i on the lane-col axis,
// matching PV's B-operand layout. The 16x16 LDS transpose collapses to 8
// cvt_pk + 8 ds_write_b32 + 8 ds_read_b32 through a 9-dword-strided pad.
// FIX vs round 7: kn/mask2 pointers advance 64 floats per j-tile (was 16).
#define OSTRIDE 51
#define WSLOT 3264          // max(576 dw pbuf, 816 dw os) bytes, 16B aligned
#define FSTRIDE 584         // 576 + 8 bf16 pad -> 16B-offset per row, conflict-free b128
__global__ __launch_bounds__(768, 3) void attn_fused(
    const unsigned short* __restrict__ qgb, const float* __restrict__ qn,
    const unsigned short* __restrict__ kgb, const unsigned short* __restrict__ vtb,
    const float* __restrict__ kn, const float* __restrict__ mask1,
    const float* __restrict__ mask2, const float* __restrict__ hwts,
    const float* __restrict__ rot, const float* __restrict__ trans,
    const unsigned short* __restrict__ woutT, const float* __restrict__ bout,
    float* __restrict__ out)
{
  __shared__ __align__(16) unsigned char ovl[12*WSLOT];          // 39168 B
  __shared__ __align__(16) unsigned short feats_s[16][FSTRIDE];  // 18688 B
  __shared__ float l_s[12][16];                                  // 768 B

  int wave = threadIdx.x >> 6;
  int lane = threadIdx.x & 63;
  int col = lane & 15, g = lane >> 4;
  int b = blockIdx.x >> 7;
  int it = blockIdx.x & 127;
  int h = wave;
  int bh = b*H_ + h;

  unsigned* pw = (unsigned*)(ovl + wave*WSLOT);  // [64 slots][9 dw] P exchange pad
  float*    os = (float*)(ovl + wave*WSLOT);     // [16][OSTRIDE] f32 (after last pw use)

  float hw   = logf(1.0f + __expf(hwts[h])) * HW_SCALE_;
  float hwl  = hw * LOG2E_;                 // log2-domain scale
  float nh   = -0.5f * hwl;
  float mneg = -INF_ * LOG2E_;

  bf16x8 qa = *(const bf16x8*)(qgb + (((size_t)bh*N1_ + it*16 + col)*32 + g*8));

  // i = col for this lane (swapped layout): single scalars
  int ig = it*16 + col;
  float ar  = nh * qn[(size_t)bh*N1_ + ig];
  float m1l = mask1[b*N1_ + ig] * (INF_*LOG2E_);
  float arm = ar + mneg;     // row-constant; rounding cancels in softmax

  f32x4 ot[3];
  #pragma unroll
  for (int m = 0; m < 3; ++m) ot[m] = (f32x4){0.f,0.f,0.f,0.f};
  float l = 0.f;

  // jt-loop pointers: per-lane bases, advanced once per jt, imm offsets inside
  const unsigned short* kptr = kgb + (size_t)bh*N2_*32 + col*32 + g*8;
  const unsigned short* vp0 = vtb + (size_t)bh*48*512 + (size_t)(     col)*512 + g*8;
  const unsigned short* vp1 = vtb + (size_t)bh*48*512 + (size_t)(16 + col)*512 + g*8;
  const unsigned short* vp2 = vtb + (size_t)bh*48*512 + (size_t)(32 + col)*512 + g*8;
  const float* knp = kn + (size_t)bh*N2_ + g*4;
  const float* m2p = mask2 + b*N2_ + g*4;

  // P exchange pad indices (dwords): write slot (col*4+g), read slots
  // (col*4 + 2(g&1)) and +1, sub-offset 2*(g>>1) + 4*ks
  int wslot = (col*4 + g)*9;
  int rbase = (col*4 + ((g&1)<<1))*9 + ((g>>1)<<1);

  for (int jt = 0; jt < 8; ++jt) {
    #pragma unroll
    for (int nt = 0; nt < 4; ++nt) {
      bf16x8 kb = *(const bf16x8*)(kptr + nt*512);
      f32x4 dotv = __builtin_amdgcn_mfma_f32_16x16x32_bf16(
          kb, qa, (f32x4){0.f,0.f,0.f,0.f}, 0, 0, 0);   // S[j=g*4+r][i=col]
      float4 knv = *(const float4*)(knp + nt*16);
      float4 m2v = *(const float4*)(m2p + nt*16);
      float w[4];
      #pragma unroll
      for (int r = 0; r < 4; ++r) {
        float t = fmaf(m1l, ((const float*)&m2v)[r], arm);
        t = fmaf(nh, ((const float*)&knv)[r], t);
        t = fmaf(hwl, dotv[r], t);
        w[r] = __builtin_amdgcn_exp2f(t);
        l += w[r];
      }
      pw[wslot + nt*2]     = cvtpk_bf16(w[0], w[1]);
      pw[wslot + nt*2 + 1] = cvtpk_bf16(w[2], w[3]);
    }
    __builtin_amdgcn_s_setprio(1);
    #pragma unroll
    for (int ks = 0; ks < 2; ++ks) {
      u32x4 pd;
      pd[0] = pw[rbase + ks*4];
      pd[1] = pw[rbase + ks*4 + 1];
      pd[2] = pw[rbase + 9 + ks*4];
      pd[3] = pw[rbase + 9 + ks*4 + 1];
      bf16x8 pb = *(bf16x8*)&pd;
      ot[0] = __builtin_amdgcn_mfma_f32_16x16x32_bf16(*(const bf16x8*)(vp0 + ks*32), pb, ot[0], 0,0,0);
      ot[1] = __builtin_amdgcn_mfma_f32_16x16x32_bf16(*(const bf16x8*)(vp1 + ks*32), pb, ot[1], 0,0,0);
      ot[2] = __builtin_amdgcn_mfma_f32_16x16x32_bf16(*(const bf16x8*)(vp2 + ks*32), pb, ot[2], 0,0,0);
    }
    __builtin_amdgcn_s_setprio(0);
    kptr += 2048; vp0 += 64; vp1 += 64; vp2 += 64; knp += 64; m2p += 64;
  }

  // l: sum over the 4 g-lanes of this col (row total), then stash with O partials
  l += __shfl_xor(l, 16);
  l += __shfl_xor(l, 32);
  __builtin_amdgcn_sched_barrier(0);   // keep os writes after the final pw reads
  if (g == 0) l_s[wave][col] = l;
  #pragma unroll
  for (int mtv = 0; mtv < 3; ++mtv)
    #pragma unroll
    for (int r = 0; r < 4; ++r)
      os[col*OSTRIDE + mtv*16 + g*4 + r] = ot[mtv][r];
  __syncthreads();

  // epilogue: rotate back to local frame, write bf16 feats slice to LDS
  {
    float inv = 1.0f / l_s[wave][col];
    int row = b*N1_ + it*16 + col;
    const float* R  = rot   + (size_t)row*9;
    const float* tr = trans + (size_t)row*3;
    float R00=R[0],R01=R[1],R02=R[2],R10=R[3],R11=R[4],R12=R[5],R20=R[6],R21=R[7],R22=R[8];
    float t0=tr[0], t1=tr[1], t2=tr[2];
    int h12 = h*PV_;
    #pragma unroll
    for (int p = 0; p < 3; ++p) {
      int pt = g*3 + p;
      float ox = os[col*OSTRIDE + pt*3+0]*inv - t0;
      float oy = os[col*OSTRIDE + pt*3+1]*inv - t1;
      float oz = os[col*OSTRIDE + pt*3+2]*inv - t2;
      float lx = R00*ox + R10*oy + R20*oz;
      float ly = R01*ox + R11*oy + R21*oz;
      float lz = R02*ox + R12*oy + R22*oz;
      float dist = sqrtf(lx*lx + ly*ly + lz*lz + 1e-8f);
      feats_s[col][      h12 + pt] = f2bf(lx);
      feats_s[col][144 + h12 + pt] = f2bf(ly);
      feats_s[col][288 + h12 + pt] = f2bf(lz);
      feats_s[col][432 + h12 + pt] = f2bf(dist);
    }
  }
  __syncthreads();

  // output projection: wave handles cols [wave*32, wave*32+32) of out
  {
    int n0 = wave * 32;
    f32x4 acc0 = {0.f,0.f,0.f,0.f}, acc1 = acc0;
    const unsigned short* b0 = woutT + (size_t)(n0      + col)*576;
    const unsigned short* b1 = woutT + (size_t)(n0 + 16 + col)*576;
    #pragma unroll 3
    for (int k = 0; k < 576; k += 32) {
      bf16x8 a = *(const bf16x8*)&feats_s[col][k + g*8];
      acc0 = __builtin_amdgcn_mfma_f32_16x16x32_bf16(a, *(const bf16x8*)(b0 + k + g*8), acc0, 0,0,0);
      acc1 = __builtin_amdgcn_mfma_f32_16x16x32_bf16(a, *(const bf16x8*)(b1 + k + g*8), acc1, 0,0,0);
    }
    int rowbase = b*N1_ + it*16;
    float bb0 = bout[n0 + col];
    float bb1 = bout[n0 + 16 + col];
    #pragma unroll
    for (int r = 0; r < 4; ++r) {
      size_t orow = (size_t)(rowbase + g*4 + r)*CS_;
      out[orow + n0 + col]      = acc0[r] + bb0;
      out[orow + n0 + 16 + col] = acc1[r] + bb1;
    }
  }
}

extern "C" void kernel_launch(void* const* d_in, const int* in_sizes, int n_in,
                              void* d_out, int out_size, void* d_ws, size_t ws_size,
                              hipStream_t stream) {
  const float* s1       = (const float*)d_in[0];
  const float* s2       = (const float*)d_in[1];
  const float* r1_rot   = (const float*)d_in[2];
  const float* r1_trans = (const float*)d_in[3];
  const float* r2_rot   = (const float*)d_in[4];
  const float* r2_trans = (const float*)d_in[5];
  const float* mask1    = (const float*)d_in[6];
  const float* mask2    = (const float*)d_in[7];
  const float* Wq       = (const float*)d_in[8];
  const float* Wkv      = (const float*)d_in[9];
  const float* hwts     = (const float*)d_in[10];
  const float* Wout     = (const float*)d_in[11];
  const float* bout     = (const float*)d_in[12];
  float* out = (float*)d_out;

  float* qn = (float*)d_ws;                              // 49152 f32
  float* kn = qn + (size_t)B_*H_*N1_;                    // 12288 f32
  unsigned short* qgb  = (unsigned short*)(kn + (size_t)B_*H_*N2_); // 1572864 u16
  unsigned short* kgb  = qgb  + (size_t)B_*H_*N1_*32;    // 393216 u16
  unsigned short* vtb  = kgb  + (size_t)B_*H_*N2_*32;    // 589824 u16
  unsigned short* wqT  = vtb  + (size_t)B_*H_*48*512;    // 110592 u16
  unsigned short* wkvT = wqT  + (size_t)CQ_*CS_;         // 276480 u16
  unsigned short* woutT= wkvT + (size_t)CKV_*CS_;        // 221184 u16
  unsigned short* s1b  = woutT+ (size_t)CS_*576;         // 1572864 u16
  unsigned short* s2b  = s1b  + (size_t)B_*N1_*CS_;      // 393216 u16

  prep_kernel<<<PREP_GRID_, 256, 0, stream>>>(
      Wq, Wkv, Wout, s1, s2, wqT, wkvT, woutT, vtb, kn, s1b, s2b);
  proj_mfma<<<624, 512, 0, stream>>>(s1b, s2b, wqT, wkvT, r1_rot, r1_trans,
                                     r2_rot, r2_trans, qgb, qn, kgb, vtb, kn);
  attn_fused<<<B_*(N1_/16), 768, 0, stream>>>(qgb, qn, kgb, vtb, kn, mask1, mask2,
                                              hwts, r1_rot, r1_trans, woutT, bout, out);
}

// Round 9
// 144.838 us; speedup vs baseline: 1.5530x; 1.0430x over previous
//
#include <hip/hip_runtime.h>
#include <math.h>

#define B_ 2
#define N1_ 2048
#define N2_ 512
#define CS_ 384
#define H_ 12
#define PQ_ 8
#define PV_ 12
#define PKV_ 20
#define CQ_ (H_*PQ_*3)    // 288
#define CKV_ (H_*PKV_*3)  // 720
#define INF_ 100000.0f
#define HW_SCALE_ 0.09622504486493764f   // sqrt(1/108)
#define LOG2E_ 1.4426950408889634f

typedef __attribute__((ext_vector_type(8))) short bf16x8;
typedef __attribute__((ext_vector_type(4))) float f32x4;

__device__ inline unsigned short f2bf(float x) {
  unsigned u = __float_as_uint(x);
  u += 0x7fffu + ((u >> 16) & 1u);      // RNE
  return (unsigned short)(u >> 16);
}

// convert 8 consecutive f32 -> bf16x8 fragment (two dwordx4 loads)
__device__ inline bf16x8 cvt8(const float* __restrict__ p) {
  float4 a = *(const float4*)p;
  float4 b = *(const float4*)(p + 4);
  bf16x8 r;
  r[0] = (short)f2bf(a.x); r[1] = (short)f2bf(a.y);
  r[2] = (short)f2bf(a.z); r[3] = (short)f2bf(a.w);
  r[4] = (short)f2bf(b.x); r[5] = (short)f2bf(b.y);
  r[6] = (short)f2bf(b.z); r[7] = (short)f2bf(b.w);
  return r;
}

// ---------------- prep: weight transposes + vtb pad + kn zero + s1/s2 -> bf16 ----------------
#define TQ_   108   // Wq  384x288: 12 k-tiles x 9 n-tiles
#define TKV_  276   // Wkv 384x720: 12 x 23 (guard n<720)
#define TWO_  216   // Wout 576x384: 18 x 12
#define VPAD_ 72    // vtb comps 36..47 = 0 (147456 elts, 8/thr)
#define KN_   12    // kn = 0 (12288 f32, 4/thr)
#define S1B_  768   // s1 -> bf16 (1572864 elts, 8/thr)
#define S2B_  192   // s2 -> bf16 (393216 elts, 8/thr)
#define PREP_GRID_ (TQ_+TKV_+TWO_+VPAD_+KN_+S1B_+S2B_)
__global__ __launch_bounds__(256) void prep_kernel(
    const float* __restrict__ Wq, const float* __restrict__ Wkv,
    const float* __restrict__ Wout,
    const float* __restrict__ s1, const float* __restrict__ s2,
    unsigned short* __restrict__ wqT, unsigned short* __restrict__ wkvT,
    unsigned short* __restrict__ woutT,
    unsigned short* __restrict__ vtb, float* __restrict__ kn,
    unsigned short* __restrict__ s1b, unsigned short* __restrict__ s2b)
{
  __shared__ float lds[32][33];
  int blk = blockIdx.x, t = threadIdx.x;
  int rr0 = t >> 5, cc = t & 31;

  const float* src = nullptr; unsigned short* dst = nullptr;
  int K = 0, N = 0, k0 = 0, n0 = 0;
  if (blk < TQ_) {
    src = Wq; dst = wqT; K = 384; N = CQ_;
    k0 = (blk % 12) * 32; n0 = (blk / 12) * 32;
  } else if (blk < TQ_ + TKV_) {
    int b2 = blk - TQ_;
    src = Wkv; dst = wkvT; K = 384; N = CKV_;
    k0 = (b2 % 12) * 32; n0 = (b2 / 12) * 32;
  } else if (blk < TQ_ + TKV_ + TWO_) {
    int b3 = blk - TQ_ - TKV_;
    src = Wout; dst = woutT; K = 576; N = CS_;
    k0 = (b3 % 18) * 32; n0 = (b3 / 18) * 32;
  } else if (blk < TQ_ + TKV_ + TWO_ + VPAD_) {
    int idx = (blk - TQ_ - TKV_ - TWO_)*256 + t;
    int f = idx * 8;
    int run = f >> 9, off = f & 511;
    int bh = run / 12, cc2 = 36 + run % 12;
    uint4 z = {0u,0u,0u,0u};
    *(uint4*)(vtb + ((size_t)bh*48 + cc2)*512 + off) = z;
    return;
  } else if (blk < TQ_ + TKV_ + TWO_ + VPAD_ + KN_) {
    int idx = (blk - TQ_ - TKV_ - TWO_ - VPAD_)*256 + t;
    float4 z = {0.f,0.f,0.f,0.f};
    *(float4*)(kn + (size_t)idx*4) = z;
    return;
  } else if (blk < TQ_ + TKV_ + TWO_ + VPAD_ + KN_ + S1B_) {
    size_t idx = (size_t)(blk - TQ_ - TKV_ - TWO_ - VPAD_ - KN_)*256 + t;
    *(bf16x8*)(s1b + idx*8) = cvt8(s1 + idx*8);
    return;
  } else {
    size_t idx = (size_t)(blk - TQ_ - TKV_ - TWO_ - VPAD_ - KN_ - S1B_)*256 + t;
    *(bf16x8*)(s2b + idx*8) = cvt8(s2 + idx*8);
    return;
  }

  #pragma unroll
  for (int rr = 0; rr < 4; ++rr) {
    int r = rr0 + rr*8;
    if (n0 + cc < N) lds[r][cc] = src[(size_t)(k0 + r)*N + n0 + cc];
  }
  __syncthreads();
  #pragma unroll
  for (int rr = 0; rr < 4; ++rr) {
    int r = rr0 + rr*8;
    if (n0 + r < N) dst[(size_t)(n0 + r)*K + k0 + cc] = f2bf(lds[cc][r]);
  }
}

// ---------------- fused Q + KV projection via MFMA, 2-way k-split, fine-grained blocks ----------------
// 1248 blocks x 256 thr (4 waves = 2 pair-slots x 2 k-halves). Blocks [0,768):
// Q (pair ids 0..1535); [768,1248): KV (0..959). Same total waves as the 624x512
// version, but 4.9 blocks/CU instead of 2.44 -> smoother CU load balance, and
// the merge barrier spans 256 threads instead of 512.
__global__ __launch_bounds__(256) void proj_mfma(
    const unsigned short* __restrict__ s1b, const unsigned short* __restrict__ s2b,
    const unsigned short* __restrict__ wqT, const unsigned short* __restrict__ wkvT,
    const float* __restrict__ r1_rot, const float* __restrict__ r1_trans,
    const float* __restrict__ r2_rot, const float* __restrict__ r2_trans,
    unsigned short* __restrict__ qgb, float* __restrict__ qn,
    unsigned short* __restrict__ kgb, unsigned short* __restrict__ vtb,
    float* __restrict__ kn)
{
  __shared__ float merge_s[2][64][13];   // stride 13: gcd(13,32)=1, conflict-free
  int wave = threadIdx.x >> 6, lane = threadIdx.x & 63;
  int col = lane & 15, g = lane >> 4;
  int pr = wave >> 1, kh = wave & 1;
  int k0 = kh * 192;

  if (blockIdx.x < 768) {
    // ---- Q projection ----
    int pid = blockIdx.x*2 + pr;         // 0..1535
    int strip = pid / 6;                 // 0..255
    int nt = pid % 6;
    int i0 = strip * 16;

    f32x4 ax = {0.f,0.f,0.f,0.f}, ay = ax, az = ax;
    const unsigned short* arow = s1b + (size_t)(i0 + col)*CS_ + k0;
    const unsigned short* bx = wqT + (size_t)((nt     )*16 + col)*CS_ + k0;
    const unsigned short* by = wqT + (size_t)((nt +  6)*16 + col)*CS_ + k0;
    const unsigned short* bz = wqT + (size_t)((nt + 12)*16 + col)*CS_ + k0;
    #pragma unroll
    for (int k = 0; k < 192; k += 32) {
      bf16x8 a = *(const bf16x8*)(arow + k + g*8);
      ax = __builtin_amdgcn_mfma_f32_16x16x32_bf16(a, *(const bf16x8*)(bx + k + g*8), ax, 0,0,0);
      ay = __builtin_amdgcn_mfma_f32_16x16x32_bf16(a, *(const bf16x8*)(by + k + g*8), ay, 0,0,0);
      az = __builtin_amdgcn_mfma_f32_16x16x32_bf16(a, *(const bf16x8*)(bz + k + g*8), az, 0,0,0);
    }
    if (kh) {
      #pragma unroll
      for (int r = 0; r < 4; ++r) {
        merge_s[pr][lane][r]     = ax[r];
        merge_s[pr][lane][4 + r] = ay[r];
        merge_s[pr][lane][8 + r] = az[r];
      }
    }
    __syncthreads();
    if (kh) return;
    #pragma unroll
    for (int r = 0; r < 4; ++r) {
      ax[r] += merge_s[pr][lane][r];
      ay[r] += merge_s[pr][lane][4 + r];
      az[r] += merge_s[pr][lane][8 + r];
    }

    int p = nt*16 + col;
    int h = p >> 3, pq = p & 7;
    float qsum[4];
    #pragma unroll
    for (int r = 0; r < 4; ++r) {
      int row = i0 + g*4 + r;
      const float* R  = r1_rot   + (size_t)row*9;
      const float* tr = r1_trans + (size_t)row*3;
      float x = ax[r], y = ay[r], z = az[r];
      float g0 = R[0]*x + R[1]*y + R[2]*z + tr[0];
      float g1 = R[3]*x + R[4]*y + R[5]*z + tr[1];
      float g2 = R[6]*x + R[7]*y + R[8]*z + tr[2];
      int b = row >> 11, i = row & (N1_-1);
      size_t rbase = ((size_t)(b*H_ + h)*N1_ + i)*32;
      qgb[rbase + pq*3]     = f2bf(g0);
      qgb[rbase + pq*3 + 1] = f2bf(g1);
      qgb[rbase + pq*3 + 2] = f2bf(g2);
      if (pq == 7) {
        uint4 z4 = {0u,0u,0u,0u};
        *(uint4*)(qgb + rbase + 24) = z4;
      }
      qsum[r] = g0*g0 + g1*g1 + g2*g2;
    }
    #pragma unroll
    for (int r = 0; r < 4; ++r) {
      qsum[r] += __shfl_xor(qsum[r], 1);
      qsum[r] += __shfl_xor(qsum[r], 2);
      qsum[r] += __shfl_xor(qsum[r], 4);
    }
    if ((col & 7) == 0) {
      int hh = nt*2 + (col >> 3);
      #pragma unroll
      for (int r = 0; r < 4; ++r) {
        int row = i0 + g*4 + r;
        int b = row >> 11, i = row & (N1_-1);
        qn[(size_t)(b*H_ + hh)*N1_ + i] = qsum[r];
      }
    }
  } else {
    // ---- KV projection ----
    int pid = (blockIdx.x - 768)*2 + pr;   // 0..959
    int strip = pid / 15;                  // 0..63
    int nt = pid % 15;                     // 0..14
    int row0 = strip * 16;

    f32x4 ax = {0.f,0.f,0.f,0.f}, ay = ax, az = ax;
    const unsigned short* arow = s2b + (size_t)(row0 + col)*CS_ + k0;
    const unsigned short* bx = wkvT + (size_t)(nt*16       + col)*CS_ + k0;
    const unsigned short* by = wkvT + (size_t)(nt*16 + 240 + col)*CS_ + k0;
    const unsigned short* bz = wkvT + (size_t)(nt*16 + 480 + col)*CS_ + k0;
    #pragma unroll
    for (int k = 0; k < 192; k += 32) {
      bf16x8 a = *(const bf16x8*)(arow + k + g*8);
      ax = __builtin_amdgcn_mfma_f32_16x16x32_bf16(a, *(const bf16x8*)(bx + k + g*8), ax, 0,0,0);
      ay = __builtin_amdgcn_mfma_f32_16x16x32_bf16(a, *(const bf16x8*)(by + k + g*8), ay, 0,0,0);
      az = __builtin_amdgcn_mfma_f32_16x16x32_bf16(a, *(const bf16x8*)(bz + k + g*8), az, 0,0,0);
    }
    if (kh) {
      #pragma unroll
      for (int r = 0; r < 4; ++r) {
        merge_s[pr][lane][r]     = ax[r];
        merge_s[pr][lane][4 + r] = ay[r];
        merge_s[pr][lane][8 + r] = az[r];
      }
    }
    __syncthreads();
    if (kh) return;
    #pragma unroll
    for (int r = 0; r < 4; ++r) {
      ax[r] += merge_s[pr][lane][r];
      ay[r] += merge_s[pr][lane][4 + r];
      az[r] += merge_s[pr][lane][8 + r];
    }

    int p = nt*16 + col;
    int h = p / PKV_, pp = p % PKV_;
    #pragma unroll
    for (int r = 0; r < 4; ++r) {
      int row = row0 + g*4 + r;
      const float* R  = r2_rot   + (size_t)row*9;
      const float* tr = r2_trans + (size_t)row*3;
      float x = ax[r], y = ay[r], z = az[r];
      float g0 = R[0]*x + R[1]*y + R[2]*z + tr[0];
      float g1 = R[3]*x + R[4]*y + R[5]*z + tr[1];
      float g2 = R[6]*x + R[7]*y + R[8]*z + tr[2];
      int b = row >> 9, j = row & (N2_-1);
      int bh = b*H_ + h;
      if (pp < PQ_) {
        size_t base = ((size_t)bh*N2_ + j)*32 + pp*3;
        kgb[base]   = f2bf(g0);
        kgb[base+1] = f2bf(g1);
        kgb[base+2] = f2bf(g2);
        if (pp == 0) {
          uint4 z4 = {0u,0u,0u,0u};
          *(uint4*)(kgb + ((size_t)bh*N2_ + j)*32 + 24) = z4;
        }
        atomicAdd(&kn[(size_t)bh*N2_ + j], g0*g0 + g1*g1 + g2*g2);
      } else {
        int comp = (pp - PQ_)*3;
        size_t base = ((size_t)bh*48 + comp)*512 + j;
        vtb[base]        = f2bf(g0);
        vtb[base + 512]  = f2bf(g1);
        vtb[base + 1024] = f2bf(g2);
      }
    }
  }
}

// ---------------- fused MFMA flash attention + output projection ----------------
// Best measured configuration (round 6 attn: 43.1 us): one block per (b, i-tile
// of 16 rows), 12 waves = 12 heads, full j-sweep per wave, 1-deep register
// prefetch, setprio(1/0) around the PV MFMA cluster.
#define RSTRIDE 72
#define OSTRIDE 51
#define WSLOT 3328          // max(16*72*2, 16*51*4) rounded to 16B; pstrip/o_s overlay
#define FSTRIDE 584         // 576 + 8 bf16 pad -> 16B-offset per row, conflict-free b128
__global__ __launch_bounds__(768, 3) void attn_fused(
    const unsigned short* __restrict__ qgb, const float* __restrict__ qn,
    const unsigned short* __restrict__ kgb, const unsigned short* __restrict__ vtb,
    const float* __restrict__ kn, const float* __restrict__ mask1,
    const float* __restrict__ mask2, const float* __restrict__ hwts,
    const float* __restrict__ rot, const float* __restrict__ trans,
    const unsigned short* __restrict__ woutT, const float* __restrict__ bout,
    float* __restrict__ out)
{
  __shared__ __align__(16) unsigned char ovl[12*WSLOT];          // 39936 B
  __shared__ __align__(16) unsigned short feats_s[16][FSTRIDE];  // 18688 B
  __shared__ float l_s[12][16];                                  // 768 B

  int wave = threadIdx.x >> 6;
  int lane = threadIdx.x & 63;
  int col = lane & 15, g = lane >> 4;
  int b = blockIdx.x >> 7;
  int it = blockIdx.x & 127;
  int h = wave;
  int bh = b*H_ + h;

  unsigned short* ps = (unsigned short*)(ovl + wave*WSLOT);  // [16][RSTRIDE] u16
  float*          os = (float*)(ovl + wave*WSLOT);           // [16][OSTRIDE] f32 (after last ps use)

  float hw   = logf(1.0f + __expf(hwts[h])) * HW_SCALE_;
  float hwl  = hw * LOG2E_;                 // log2-domain scale
  float mneg = -INF_ * LOG2E_;

  bf16x8 qa = *(const bf16x8*)(qgb + (((size_t)bh*N1_ + it*16 + col)*32 + g*8));

  float ar[4], m1l[4];
  #pragma unroll
  for (int r = 0; r < 4; ++r) {
    int ig = it*16 + g*4 + r;
    ar[r]  = -0.5f*hwl * qn[(size_t)bh*N1_ + ig];
    m1l[r] = mask1[b*N1_ + ig] * (INF_*LOG2E_);   // fma(m1l, m2, mneg) == 0 exactly when unmasked
  }

  f32x4 ot[3];
  #pragma unroll
  for (int m = 0; m < 3; ++m) ot[m] = (f32x4){0.f,0.f,0.f,0.f};
  float l[4] = {0.f,0.f,0.f,0.f};

  const unsigned short* kbase = kgb + (size_t)bh*N2_*32;
  const unsigned short* vbase = vtb + (size_t)bh*48*512;
  const float* knp = kn + (size_t)bh*N2_;
  const float* m2p = mask2 + b*N2_;

  // ---- software pipeline: register-prefetch next j-tile's K/V/scalars ----
  bf16x8 kbuf[4], vbuf[6];
  float knb[4], m2b[4];
  #pragma unroll
  for (int nt = 0; nt < 4; ++nt) {
    int jg = nt*16 + col;
    kbuf[nt] = *(const bf16x8*)(kbase + ((size_t)jg*32 + g*8));
    knb[nt] = knp[jg];
    m2b[nt] = m2p[jg];
  }
  #pragma unroll
  for (int ks = 0; ks < 2; ++ks)
    #pragma unroll
    for (int mtv = 0; mtv < 3; ++mtv)
      vbuf[ks*3 + mtv] = *(const bf16x8*)(vbase +
          ((size_t)(mtv*16 + col))*512 + ks*32 + g*8);

  for (int jt = 0; jt < 8; ++jt) {
    int j0 = jt*64;
    bf16x8 kNx[4], vNx[6];
    float knN[4], m2N[4];
    if (jt < 7) {
      int j1 = j0 + 64;
      #pragma unroll
      for (int nt = 0; nt < 4; ++nt) {
        int jg = j1 + nt*16 + col;
        kNx[nt] = *(const bf16x8*)(kbase + ((size_t)jg*32 + g*8));
        knN[nt] = knp[jg];
        m2N[nt] = m2p[jg];
      }
      #pragma unroll
      for (int ks = 0; ks < 2; ++ks)
        #pragma unroll
        for (int mtv = 0; mtv < 3; ++mtv)
          vNx[ks*3 + mtv] = *(const bf16x8*)(vbase +
              ((size_t)(mtv*16 + col))*512 + j1 + ks*32 + g*8);
    }

    #pragma unroll
    for (int nt = 0; nt < 4; ++nt) {
      f32x4 dotv = __builtin_amdgcn_mfma_f32_16x16x32_bf16(
          qa, kbuf[nt], (f32x4){0.f,0.f,0.f,0.f}, 0, 0, 0);
      float bc  = -0.5f*hwl*knb[nt];
      float m2c = m2b[nt];
      #pragma unroll
      for (int r = 0; r < 4; ++r) {
        float logit = fmaf(hwl, dotv[r], fmaf(m1l[r], m2c, mneg) + (ar[r] + bc));
        float w = __builtin_amdgcn_exp2f(logit);   // logit <= 0 -> w <= 1
        l[r] += w;
        ps[(g*4 + r)*RSTRIDE + nt*16 + col] = f2bf(w);
      }
    }
    __builtin_amdgcn_s_setprio(1);
    #pragma unroll
    for (int ks = 0; ks < 2; ++ks) {
      bf16x8 pb = *(const bf16x8*)&ps[col*RSTRIDE + ks*32 + g*8];
      #pragma unroll
      for (int mtv = 0; mtv < 3; ++mtv)
        ot[mtv] = __builtin_amdgcn_mfma_f32_16x16x32_bf16(vbuf[ks*3 + mtv], pb, ot[mtv], 0, 0, 0);
    }
    __builtin_amdgcn_s_setprio(0);

    if (jt < 7) {
      #pragma unroll
      for (int i = 0; i < 4; ++i) { kbuf[i] = kNx[i]; knb[i] = knN[i]; m2b[i] = m2N[i]; }
      #pragma unroll
      for (int i = 0; i < 6; ++i) vbuf[i] = vNx[i];
    }
  }

  // reduce l over the 16 cols; stash l and O partials in LDS
  #pragma unroll
  for (int r = 0; r < 4; ++r) {
    l[r] += __shfl_xor(l[r], 1);
    l[r] += __shfl_xor(l[r], 2);
    l[r] += __shfl_xor(l[r], 4);
    l[r] += __shfl_xor(l[r], 8);
  }
  __builtin_amdgcn_sched_barrier(0);   // keep os writes after the final ps reads
  if (col == 0) {
    #pragma unroll
    for (int r = 0; r < 4; ++r) l_s[wave][g*4 + r] = l[r];
  }
  #pragma unroll
  for (int mtv = 0; mtv < 3; ++mtv)
    #pragma unroll
    for (int r = 0; r < 4; ++r)
      os[col*OSTRIDE + mtv*16 + g*4 + r] = ot[mtv][r];
  __syncthreads();

  // epilogue: rotate back to local frame, write bf16 feats slice to LDS
  {
    float inv = 1.0f / l_s[wave][col];
    int ig = it*16 + col;
    int row = b*N1_ + ig;
    const float* R  = rot   + (size_t)row*9;
    const float* tr = trans + (size_t)row*3;
    float R00=R[0],R01=R[1],R02=R[2],R10=R[3],R11=R[4],R12=R[5],R20=R[6],R21=R[7],R22=R[8];
    float t0=tr[0], t1=tr[1], t2=tr[2];
    int h12 = h*PV_;
    #pragma unroll
    for (int p = 0; p < 3; ++p) {
      int pt = g*3 + p;
      float ox = os[col*OSTRIDE + pt*3+0]*inv - t0;
      float oy = os[col*OSTRIDE + pt*3+1]*inv - t1;
      float oz = os[col*OSTRIDE + pt*3+2]*inv - t2;
      float lx = R00*ox + R10*oy + R20*oz;
      float ly = R01*ox + R11*oy + R21*oz;
      float lz = R02*ox + R12*oy + R22*oz;
      float dist = sqrtf(lx*lx + ly*ly + lz*lz + 1e-8f);
      feats_s[col][      h12 + pt] = f2bf(lx);
      feats_s[col][144 + h12 + pt] = f2bf(ly);
      feats_s[col][288 + h12 + pt] = f2bf(lz);
      feats_s[col][432 + h12 + pt] = f2bf(dist);
    }
  }
  __syncthreads();

  // output projection: wave handles cols [wave*32, wave*32+32) of out
  {
    int n0 = wave * 32;
    f32x4 acc0 = {0.f,0.f,0.f,0.f}, acc1 = acc0;
    const unsigned short* b0 = woutT + (size_t)(n0      + col)*576;
    const unsigned short* b1 = woutT + (size_t)(n0 + 16 + col)*576;
    #pragma unroll 3
    for (int k = 0; k < 576; k += 32) {
      bf16x8 a = *(const bf16x8*)&feats_s[col][k + g*8];
      acc0 = __builtin_amdgcn_mfma_f32_16x16x32_bf16(a, *(const bf16x8*)(b0 + k + g*8), acc0, 0,0,0);
      acc1 = __builtin_amdgcn_mfma_f32_16x16x32_bf16(a, *(const bf16x8*)(b1 + k + g*8), acc1, 0,0,0);
    }
    int rowbase = b*N1_ + it*16;
    float bb0 = bout[n0 + col];
    float bb1 = bout[n0 + 16 + col];
    #pragma unroll
    for (int r = 0; r < 4; ++r) {
      size_t orow = (size_t)(rowbase + g*4 + r)*CS_;
      out[orow + n0 + col]      = acc0[r] + bb0;
      out[orow + n0 + 16 + col] = acc1[r] + bb1;
    }
  }
}

extern "C" void kernel_launch(void* const* d_in, const int* in_sizes, int n_in,
                              void* d_out, int out_size, void* d_ws, size_t ws_size,
                              hipStream_t stream) {
  const float* s1       = (const float*)d_in[0];
  const float* s2       = (const float*)d_in[1];
  const float* r1_rot   = (const float*)d_in[2];
  const float* r1_trans = (const float*)d_in[3];
  const float* r2_rot   = (const float*)d_in[4];
  const float* r2_trans = (const float*)d_in[5];
  const float* mask1    = (const float*)d_in[6];
  const float* mask2    = (const float*)d_in[7];
  const float* Wq       = (const float*)d_in[8];
  const float* Wkv      = (const float*)d_in[9];
  const float* hwts     = (const float*)d_in[10];
  const float* Wout     = (const float*)d_in[11];
  const float* bout     = (const float*)d_in[12];
  float* out = (float*)d_out;

  float* qn = (float*)d_ws;                              // 49152 f32
  float* kn = qn + (size_t)B_*H_*N1_;                    // 12288 f32
  unsigned short* qgb  = (unsigned short*)(kn + (size_t)B_*H_*N2_); // 1572864 u16
  unsigned short* kgb  = qgb  + (size_t)B_*H_*N1_*32;    // 393216 u16
  unsigned short* vtb  = kgb  + (size_t)B_*H_*N2_*32;    // 589824 u16
  unsigned short* wqT  = vtb  + (size_t)B_*H_*48*512;    // 110592 u16
  unsigned short* wkvT = wqT  + (size_t)CQ_*CS_;         // 276480 u16
  unsigned short* woutT= wkvT + (size_t)CKV_*CS_;        // 221184 u16
  unsigned short* s1b  = woutT+ (size_t)CS_*576;         // 1572864 u16
  unsigned short* s2b  = s1b  + (size_t)B_*N1_*CS_;      // 393216 u16

  prep_kernel<<<PREP_GRID_, 256, 0, stream>>>(
      Wq, Wkv, Wout, s1, s2, wqT, wkvT, woutT, vtb, kn, s1b, s2b);
  proj_mfma<<<1248, 256, 0, stream>>>(s1b, s2b, wqT, wkvT, r1_rot, r1_trans,
                                      r2_rot, r2_trans, qgb, qn, kgb, vtb, kn);
  attn_fused<<<B_*(N1_/16), 768, 0, stream>>>(qgb, qn, kgb, vtb, kn, mask1, mask2,
                                              hwts, r1_rot, r1_trans, woutT, bout, out);
}